// Round 9
// baseline (1429.838 us; speedup 1.0000x reference)
//
#include <hip/hip_runtime.h>

#define NB    8
#define NPTS  8192
#define NCTR  1024
#define KNN   64
#define NGRP  8192
#define SAMP  524288
#define EPSB  1e-5f

// ---- ws layout (bytes), total SMALL ~36 MB, BIG ~170 MB ----
#define OFF_CIDX 0ull
#define OFF_NIDX 32768ull
#define OFF_SS   2129920ull
#define OFF_PSUM 2134016ull            // 4096*256*4 = 4 MB
#define OFF_PSQR 6328320ull            // 4 MB
#define OFF_GMAX 10522624ull           // 8 MB
#define OFF_GMIN 18911232ull           // 8 MB
#define OFF_FT   27299840ull           // 8 MB
#define OFF_Y1   35688448ull           // 134 MB (BIG only)
#define NEED_BIG 169906176ull

typedef unsigned short ushort8 __attribute__((ext_vector_type(8)));
typedef short short8v __attribute__((ext_vector_type(8)));
typedef float f32x4 __attribute__((ext_vector_type(4)));

__device__ __forceinline__ unsigned short f2b(float f) {
  unsigned int u = __builtin_bit_cast(unsigned int, f);
  u += 0x7fffu + ((u >> 16) & 1u);
  return (unsigned short)(u >> 16);
}
__device__ __forceinline__ float b2f(unsigned short s) {
  unsigned int u = ((unsigned int)s) << 16;
  return __builtin_bit_cast(float, u);
}

// DPP-assisted max step: r = max(r, dpp_move(r)) ; bound_ctrl=1 -> invalid src reads 0.0
template <int CTRL>
__device__ __forceinline__ float dppmax(float x) {
  int m = __builtin_amdgcn_update_dpp(0, __builtin_bit_cast(int, x), CTRL, 0xf, 0xf, true);
  return fmaxf(x, __builtin_bit_cast(float, m));
}

// ---------------- FPS (R5 version, best known): 4 waves, DPP wave-max + ballot ----------------
__global__ __launch_bounds__(256) void fps_kernel(const float* __restrict__ coords,
                                                  int* __restrict__ cidx,
                                                  float* __restrict__ centers_out) {
  const int b = blockIdx.x;
  const int t = threadIdx.x;
  const int wid = t >> 6, lane = t & 63;
  __shared__ float4 sc4[NPTS];                 // 128 KB packed coords
  __shared__ unsigned long long red[2][4];
  const float* cb = coords + (size_t)b * 3 * NPTS;
  for (int i = t; i < NPTS; i += 256)
    sc4[i] = make_float4(cb[i], cb[NPTS + i], cb[2 * NPTS + i], 0.f);
  __syncthreads();
  constexpr int PT = NPTS / 256;  // 32, contiguous per thread
  float px[PT], py[PT], pz[PT], dst[PT];
#pragma unroll
  for (int i = 0; i < PT; ++i) {
    int p = t * PT + i;
    px[i] = cb[p]; py[i] = cb[NPTS + p]; pz[i] = cb[2 * NPTS + p];
    dst[i] = 1e10f;
  }
  int cur = 0;
  float4 c0 = sc4[0];
  float cx = c0.x, cy = c0.y, cz = c0.z;
  int parity = 0;
  for (int s = 0; s < NCTR; ++s) {
    if (t == 0) {
      cidx[b * NCTR + s] = cur;
      centers_out[(b * 3 + 0) * NCTR + s] = cx;
      centers_out[(b * 3 + 1) * NCTR + s] = cy;
      centers_out[(b * 3 + 2) * NCTR + s] = cz;
    }
    float bv = -1.0f; int bi = 0;
#pragma unroll
    for (int i = 0; i < PT; ++i) {
      // exact numpy f32 order: ((dx*dx + dy*dy) + dz*dz), no fma contraction
      float dx = __fsub_rn(px[i], cx);
      float dy = __fsub_rn(py[i], cy);
      float dz = __fsub_rn(pz[i], cz);
      float d2 = __fadd_rn(__fadd_rn(__fmul_rn(dx, dx), __fmul_rn(dy, dy)), __fmul_rn(dz, dz));
      float nd = fminf(dst[i], d2);
      dst[i] = nd;
      if (nd > bv) { bv = nd; bi = t * PT + i; }   // ascending i -> first occurrence
    }
    float r = bv;
    r = dppmax<0x111>(r);
    r = dppmax<0x112>(r);
    r = dppmax<0x114>(r);
    r = dppmax<0x118>(r);
    r = dppmax<0x142>(r);
    r = dppmax<0x143>(r);
    float wm = __builtin_bit_cast(float,
        __builtin_amdgcn_readlane(__builtin_bit_cast(int, r), 63));
    unsigned long long mask = __ballot(bv == wm);
    int widx = __shfl(bi, (int)__builtin_ctzll(mask));  // lowest lane == smallest index
    if (lane == 0)
      red[parity][wid] =
          ((unsigned long long)__builtin_bit_cast(unsigned int, wm) << 32) |
          (unsigned long long)(~(unsigned int)widx);
    __syncthreads();
    unsigned long long best = red[parity][0];
#pragma unroll
    for (int k = 1; k < 4; ++k) {
      unsigned long long o = red[parity][k];
      best = (o > best) ? o : best;
    }
    cur = (int)(~(unsigned int)best);
    float4 cc = sc4[cur];                       // single b128 LDS broadcast
    cx = cc.x; cy = cc.y; cz = cc.z;
    parity ^= 1;
  }
}

// ---------------- feat transpose to [B][N][64] bf16 ----------------
__global__ __launch_bounds__(256) void featT_kernel(const float* __restrict__ feat,
                                                    unsigned short* __restrict__ fT) {
  int b  = blockIdx.y;
  int j  = blockIdx.x * 64 + (threadIdx.x & 63);
  int cg = threadIdx.x >> 6;
  ushort8 v0, v1;
#pragma unroll
  for (int cc = 0; cc < 8; ++cc)
    v0[cc] = f2b(feat[((size_t)b * 64 + cg * 16 + cc) * NPTS + j]);
#pragma unroll
  for (int cc = 0; cc < 8; ++cc)
    v1[cc] = f2b(feat[((size_t)b * 64 + cg * 16 + 8 + cc) * NPTS + j]);
  unsigned short* dst = fT + ((size_t)b * NPTS + j) * 64 + cg * 16;
  *(ushort8*)dst = v0;
  *(ushort8*)(dst + 8) = v1;
}

// ---------------- ball query: wave per center, stream coords from L2 ----------------
__global__ __launch_bounds__(256) void bq_kernel(const float* __restrict__ coords,
                                                 const int* __restrict__ cidx,
                                                 int* __restrict__ nidx) {
  const int b = blockIdx.y;
  const int w = threadIdx.x >> 6, lane = threadIdx.x & 63;
  const int m = blockIdx.x * 4 + w;
  const float* cb = coords + (size_t)b * 3 * NPTS;
  const int cen = cidx[b * NCTR + m];
  const float cx = cb[cen], cy = cb[NPTS + cen], cz = cb[2 * NPTS + cen];
  int* outp = nidx + ((size_t)b * NCTR + m) * KNN;
  const float RR = (float)(0.2 * 0.2);   // exact f64->f32 like numpy
  int found = 0, first = -1;
  for (int chunk = 0; chunk < NPTS / 64 && found < KNN; ++chunk) {
    int p = chunk * 64 + lane;
    float dx = __fsub_rn(cx, cb[p]);
    float dy = __fsub_rn(cy, cb[NPTS + p]);
    float dz = __fsub_rn(cz, cb[2 * NPTS + p]);
    float d2 = __fadd_rn(__fadd_rn(__fmul_rn(dx, dx), __fmul_rn(dy, dy)), __fmul_rn(dz, dz));
    bool pred = d2 < RR;
    unsigned long long mask = __ballot(pred);
    if (pred) {
      int rank = __popcll(mask & ((1ull << lane) - 1ull));
      int slot = found + rank;
      if (slot < KNN) outp[slot] = p;
    }
    if (first < 0 && mask != 0ull) first = chunk * 64 + __builtin_ctzll(mask);
    found += __popcll(mask);
  }
  if (found < KNN) {
    int f = (first < 0) ? 0 : first;
    if (lane >= found) outp[lane] = f;
  }
}

// ---------------- fused conv chain: 256 thr, 2 groups/block, 2 waves/group ----------------
// wv = wg2*2 + hp; pair (wg2, hp=0/1) shares group wg2's X tile, splits output
// channels [hp*64, hp*64+64). LDS ~70 KB -> 2 independent blocks/CU.
// NL=1: conv0 -> stats0.  NL=2: conv0->bn0->conv1 -> stats1 (+y1 if WRITEY1).
// NL=3: (READY1 ? y1 : conv0->bn0->conv1) -> bn1 -> conv2 -> per-group max/min + stats2.
template <int NL, bool READY1, bool WRITEY1>
__global__ __launch_bounds__(256) void fused_kernel(
    const unsigned short* __restrict__ fT, const float* __restrict__ coords,
    const int* __restrict__ cidx, const int* __restrict__ nidx,
    unsigned short* __restrict__ y1, const float* __restrict__ ss,
    const float* __restrict__ w0, const float* __restrict__ b0,
    const float* __restrict__ w1, const float* __restrict__ b1,
    const float* __restrict__ w2, const float* __restrict__ b2,
    float* __restrict__ psum, float* __restrict__ psqr,
    float* __restrict__ gmax, float* __restrict__ gmin) {
  __shared__ __align__(16) unsigned short Xs[2 * 64 * 128];   // 32 KB
  __shared__ __align__(16) unsigned short Wbuf[128 * 128];    // 32 KB
  __shared__ float s_bias[128];
  __shared__ float s_sc0[128], s_sh0[128], s_sc1[128], s_sh1[128];
  __shared__ float s_rs[4][64], s_rq[4][64];

  const int t = threadIdx.x;
  const int wv = t >> 6, lane = t & 63;
  const int wg2 = wv >> 1;         // local group 0..1
  const int hp = wv & 1;           // output-half parity
  const int r16 = lane & 15, kg = lane >> 4;
  const int g = blockIdx.x * 2 + wg2;
  const int bb_ = g >> 10;
  const int rsw = lane & 7;
  unsigned short* xrow = &Xs[(wg2 * 64 + lane) * 128];

  if constexpr (NL >= 2 && !READY1) {
    if (t < 128) { s_sc0[t] = ss[t]; s_sh0[t] = ss[128 + t]; }
  }
  if constexpr (NL >= 3) {
    if (t < 128) { s_sc1[t] = ss[256 + t]; s_sh1[t] = ss[384 + t]; }
  }

  auto stageW = [&](const float* w, const float* bia, bool remap0, int oh) {
    for (int e = t; e < 128 * 128; e += 256) {
      int o = e >> 7, c = e & 127;
      float v;
      if (remap0) {
        int lc = (c < 64) ? (c + 3) : ((c < 67) ? (c - 64) : -1);
        v = (lc >= 0) ? w[o * 67 + lc] : 0.f;
      } else {
        v = w[((size_t)(oh * 128 + o)) * 128 + c];
      }
      Wbuf[(o << 7) + ((((c >> 3) ^ (o & 7)) << 3) | (c & 7))] = f2b(v);
    }
    if (t < 128) s_bias[t] = bia[oh * 128 + t];
  };

  // per-wave partials over its 4 nt tiles (channels hp*64 + k*16 + r16)
  auto statsOut = [&](float (&sv4)[4], float (&sq4)[4], int coff) {
#pragma unroll
    for (int k = 0; k < 4; ++k) {
      sv4[k] += __shfl_xor(sv4[k], 16); sv4[k] += __shfl_xor(sv4[k], 32);
      sq4[k] += __shfl_xor(sq4[k], 16); sq4[k] += __shfl_xor(sq4[k], 32);
    }
    if (lane < 16) {
#pragma unroll
      for (int k = 0; k < 4; ++k) {
        s_rs[wv][k * 16 + lane] = sv4[k];
        s_rq[wv][k * 16 + lane] = sq4[k];
      }
    }
    __syncthreads();
    if (t < 128) {
      int hp2 = t >> 6, cl = t & 63;
      float sB = s_rs[hp2][cl] + s_rs[2 + hp2][cl];
      float qB = s_rq[hp2][cl] + s_rq[2 + hp2][cl];
      psum[(size_t)blockIdx.x * 256 + coff + t] = sB;
      psqr[(size_t)blockIdx.x * 256 + coff + t] = qB;
    }
  };

  short8v a[4][4];

  if constexpr (!READY1) {
    if (hp == 0) {  // even wave stages its group's X0 (lane = row)
      int j = nidx[(size_t)g * KNN + lane];
      int cen = cidx[g];
      const unsigned short* fr = fT + ((size_t)bb_ * NPTS + j) * 64;
#pragma unroll
      for (int ch = 0; ch < 8; ++ch)
        *(ushort8*)(xrow + ((ch ^ rsw) << 3)) = *(const ushort8*)(fr + ch * 8);
      const float* cb = coords + (size_t)bb_ * 3 * NPTS;
      float rx = __fsub_rn(cb[j], cb[cen]);
      float ry = __fsub_rn(cb[NPTS + j], cb[NPTS + cen]);
      float rz = __fsub_rn(cb[2 * NPTS + j], cb[2 * NPTS + cen]);
      ushort8 rv = {f2b(rx), f2b(ry), f2b(rz), 0, 0, 0, 0, 0};
      *(ushort8*)(xrow + ((8 ^ rsw) << 3)) = rv;
      ushort8 zz = {0, 0, 0, 0, 0, 0, 0, 0};
#pragma unroll
      for (int ch = 9; ch < 16; ++ch)
        *(ushort8*)(xrow + ((ch ^ rsw) << 3)) = zz;
    }
    stageW(w0, b0, true, 0);
    __syncthreads();

    // ---- layer 0 ----
#pragma unroll
    for (int st = 0; st < 4; ++st) {
      int row = st * 16 + r16;
#pragma unroll
      for (int ks = 0; ks < 3; ++ks)
        a[st][ks] = __builtin_bit_cast(short8v,
            *(const ushort8*)&Xs[(wg2 * 64 + row) * 128 + (((ks * 4 + kg) ^ (row & 7)) << 3)]);
    }
    if constexpr (NL >= 2) __syncthreads();   // all a-loads done before epilogue Xs writes
    {
      float sv4[4], sq4[4];
#pragma unroll
      for (int k = 0; k < 4; ++k) { sv4[k] = 0.f; sq4[k] = 0.f; }
#pragma unroll
      for (int k = 0; k < 4; ++k) {
        int o = hp * 64 + k * 16 + r16;
        short8v wb[3];
#pragma unroll
        for (int ks = 0; ks < 3; ++ks)
          wb[ks] = __builtin_bit_cast(short8v,
              *(const ushort8*)&Wbuf[(o << 7) + (((ks * 4 + kg) ^ (o & 7)) << 3)]);
        float bia = s_bias[o];
        float sc = 0.f, sh = 0.f;
        if constexpr (NL >= 2) { sc = s_sc0[o]; sh = s_sh0[o]; }
#pragma unroll
        for (int st = 0; st < 4; ++st) {
          f32x4 acc = {0.f, 0.f, 0.f, 0.f};
#pragma unroll
          for (int ks = 0; ks < 3; ++ks)
            acc = __builtin_amdgcn_mfma_f32_16x16x32_bf16(a[st][ks], wb[ks], acc, 0, 0, 0);
#pragma unroll
          for (int r = 0; r < 4; ++r) {
            float v = acc[r] + bia;
            if constexpr (NL == 1) {
              sv4[k] += v; sq4[k] = fmaf(v, v, sq4[k]);
            } else {
              float x = fmaxf(fmaf(v, sc, sh), 0.f);
              int row = st * 16 + kg * 4 + r;
              Xs[(wg2 * 64 + row) * 128 + ((((o >> 3) ^ (row & 7)) << 3) | (o & 7))] = f2b(x);
            }
          }
        }
      }
      if constexpr (NL == 1) { statsOut(sv4, sq4, 0); return; }
    }

    // ---- layer 1 ----
    if constexpr (NL >= 2) {
      __syncthreads();
      stageW(w1, b1, false, 0);
      __syncthreads();
#pragma unroll
      for (int st = 0; st < 4; ++st) {
        int row = st * 16 + r16;
#pragma unroll
        for (int ks = 0; ks < 4; ++ks)
          a[st][ks] = __builtin_bit_cast(short8v,
              *(const ushort8*)&Xs[(wg2 * 64 + row) * 128 + (((ks * 4 + kg) ^ (row & 7)) << 3)]);
      }
      if constexpr (NL >= 3) __syncthreads();   // protect partner a-loads from bn1 writes
      float sv4[4], sq4[4];
#pragma unroll
      for (int k = 0; k < 4; ++k) { sv4[k] = 0.f; sq4[k] = 0.f; }
#pragma unroll
      for (int k = 0; k < 4; ++k) {
        int o = hp * 64 + k * 16 + r16;
        short8v wb[4];
#pragma unroll
        for (int ks = 0; ks < 4; ++ks)
          wb[ks] = __builtin_bit_cast(short8v,
              *(const ushort8*)&Wbuf[(o << 7) + (((ks * 4 + kg) ^ (o & 7)) << 3)]);
        float bia = s_bias[o];
        float sc = 0.f, sh = 0.f;
        if constexpr (NL >= 3) { sc = s_sc1[o]; sh = s_sh1[o]; }
#pragma unroll
        for (int st = 0; st < 4; ++st) {
          f32x4 acc = {0.f, 0.f, 0.f, 0.f};
#pragma unroll
          for (int ks = 0; ks < 4; ++ks)
            acc = __builtin_amdgcn_mfma_f32_16x16x32_bf16(a[st][ks], wb[ks], acc, 0, 0, 0);
#pragma unroll
          for (int r = 0; r < 4; ++r) {
            float v = acc[r] + bia;
            int row = st * 16 + kg * 4 + r;
            if constexpr (NL == 2) {
              sv4[k] += v; sq4[k] = fmaf(v, v, sq4[k]);
              if constexpr (WRITEY1)
                y1[((size_t)g * 64 + row) * 128 + o] = f2b(v);
            } else {
              float x = fmaxf(fmaf(v, sc, sh), 0.f);
              Xs[(wg2 * 64 + row) * 128 + ((((o >> 3) ^ (row & 7)) << 3) | (o & 7))] = f2b(x);
            }
          }
        }
      }
      if constexpr (NL == 2) { statsOut(sv4, sq4, 0); return; }
    }
  } else {
    // READY1 (NL==3): even wave stages X2 = relu(bn1(y1)) for its group
    __syncthreads();   // s_sc1/s_sh1 ready
    if (hp == 0) {
      const unsigned short* yr = y1 + ((size_t)g * 64 + lane) * 128;
#pragma unroll
      for (int ch = 0; ch < 16; ++ch) {
        ushort8 vv = *(const ushort8*)(yr + ch * 8);
        ushort8 ov;
#pragma unroll
        for (int jj = 0; jj < 8; ++jj) {
          int c = ch * 8 + jj;
          ov[jj] = f2b(fmaxf(fmaf(b2f(vv[jj]), s_sc1[c], s_sh1[c]), 0.f));
        }
        *(ushort8*)(xrow + ((ch ^ rsw) << 3)) = ov;
      }
    }
  }

  // ---- layer 2 (NL==3): two output halves, max/min + stats ----
  if constexpr (NL == 3) {
    __syncthreads();   // X2 tile complete (staged/written by partner waves)
#pragma unroll
    for (int st = 0; st < 4; ++st) {
      int row = st * 16 + r16;
#pragma unroll
      for (int ks = 0; ks < 4; ++ks)
        a[st][ks] = __builtin_bit_cast(short8v,
            *(const ushort8*)&Xs[(wg2 * 64 + row) * 128 + (((ks * 4 + kg) ^ (row & 7)) << 3)]);
    }
    for (int h = 0; h < 2; ++h) {
      __syncthreads();
      stageW(w2, b2, false, h);
      __syncthreads();
      float mx4[4], mn4[4], sv4[4], sq4[4];
#pragma unroll
      for (int k = 0; k < 4; ++k) { mx4[k] = -1e30f; mn4[k] = 1e30f; sv4[k] = 0.f; sq4[k] = 0.f; }
#pragma unroll
      for (int k = 0; k < 4; ++k) {
        int o = hp * 64 + k * 16 + r16;
        short8v wb[4];
#pragma unroll
        for (int ks = 0; ks < 4; ++ks)
          wb[ks] = __builtin_bit_cast(short8v,
              *(const ushort8*)&Wbuf[(o << 7) + (((ks * 4 + kg) ^ (o & 7)) << 3)]);
        float bia = s_bias[o];
#pragma unroll
        for (int st = 0; st < 4; ++st) {
          f32x4 acc = {0.f, 0.f, 0.f, 0.f};
#pragma unroll
          for (int ks = 0; ks < 4; ++ks)
            acc = __builtin_amdgcn_mfma_f32_16x16x32_bf16(a[st][ks], wb[ks], acc, 0, 0, 0);
#pragma unroll
          for (int r = 0; r < 4; ++r) {
            float v = acc[r] + bia;
            mx4[k] = fmaxf(mx4[k], v); mn4[k] = fminf(mn4[k], v);
            sv4[k] += v; sq4[k] = fmaf(v, v, sq4[k]);
          }
        }
      }
#pragma unroll
      for (int k = 0; k < 4; ++k) {
        mx4[k] = fmaxf(mx4[k], __shfl_xor(mx4[k], 16));
        mx4[k] = fmaxf(mx4[k], __shfl_xor(mx4[k], 32));
        mn4[k] = fminf(mn4[k], __shfl_xor(mn4[k], 16));
        mn4[k] = fminf(mn4[k], __shfl_xor(mn4[k], 32));
      }
      if (lane < 16) {
#pragma unroll
        for (int k = 0; k < 4; ++k) {
          gmax[(size_t)g * 256 + h * 128 + hp * 64 + k * 16 + lane] = mx4[k];
          gmin[(size_t)g * 256 + h * 128 + hp * 64 + k * 16 + lane] = mn4[k];
        }
      }
      statsOut(sv4, sq4, h * 128);
    }
  }
}

// ---------------- stats finalize (4096 partial rows) ----------------
template <int O>
__global__ __launch_bounds__(256) void ss_kernel(const float* __restrict__ psum,
                                                 const float* __restrict__ psqr,
                                                 const float* __restrict__ gamma,
                                                 const float* __restrict__ beta,
                                                 float* __restrict__ ss_out) {
  int c = blockIdx.x;
  int t = threadIdx.x;
  float s = 0.f, q = 0.f;
  for (int i = t; i < 4096; i += 256) {
    s += psum[(size_t)i * 256 + c];
    q += psqr[(size_t)i * 256 + c];
  }
  int lane = t & 63, wid = t >> 6;
#pragma unroll
  for (int off = 32; off > 0; off >>= 1) { s += __shfl_down(s, off); q += __shfl_down(q, off); }
  __shared__ float rv[4], rqv[4];
  if (lane == 0) { rv[wid] = s; rqv[wid] = q; }
  __syncthreads();
  if (t == 0) {
    s = rv[0] + rv[1] + rv[2] + rv[3];
    q = rqv[0] + rqv[1] + rqv[2] + rqv[3];
    const float inv = 1.0f / (float)SAMP;
    float mu = s * inv;
    float var = fmaxf(q * inv - mu * mu, 0.f);
    float rs = 1.0f / sqrtf(var + EPSB);
    float sc = gamma[c] * rs;
    ss_out[c] = sc;
    ss_out[O + c] = beta[c] - mu * sc;
  }
}

// ---------------- final: out = relu(max(sc*mx+sh, sc*mn+sh)), LDS transpose ----------------
__global__ __launch_bounds__(256) void final_kernel(const float* __restrict__ gmax,
                                                    const float* __restrict__ gmin,
                                                    const float* __restrict__ ss2,
                                                    float* __restrict__ out) {
  int b = blockIdx.x >> 5, mt = blockIdx.x & 31;
  int t = threadIdx.x;
  __shared__ float tile[32][257];
  float sc = ss2[t], sh = ss2[256 + t];
  size_t base = ((size_t)b * 1024 + mt * 32) * 256;
#pragma unroll
  for (int r = 0; r < 32; ++r) {
    float A = fmaf(gmax[base + r * 256 + t], sc, sh);
    float C = fmaf(gmin[base + r * 256 + t], sc, sh);
    tile[r][t] = fmaxf(fmaxf(A, C), 0.f);
  }
  __syncthreads();
  for (int i = t; i < 8192; i += 256) {
    int o = i >> 5, ml = i & 31;
    out[((size_t)b * 256 + o) * 1024 + mt * 32 + ml] = tile[ml][o];
  }
}

__global__ void cond_kernel(const float* __restrict__ cond, float* __restrict__ dst) {
  dst[threadIdx.x] = cond[threadIdx.x];
}

extern "C" void kernel_launch(void* const* d_in, const int* in_sizes, int n_in,
                              void* d_out, int out_size, void* d_ws, size_t ws_size,
                              hipStream_t stream) {
  const float* feat   = (const float*)d_in[0];
  const float* coords = (const float*)d_in[1];
  const float* cond   = (const float*)d_in[2];
  const float* w0  = (const float*)d_in[3];
  const float* b0  = (const float*)d_in[4];
  const float* ga0 = (const float*)d_in[5];
  const float* be0 = (const float*)d_in[6];
  const float* w1  = (const float*)d_in[7];
  const float* b1  = (const float*)d_in[8];
  const float* ga1 = (const float*)d_in[9];
  const float* be1 = (const float*)d_in[10];
  const float* w2  = (const float*)d_in[11];
  const float* b2  = (const float*)d_in[12];
  const float* ga2 = (const float*)d_in[13];
  const float* be2 = (const float*)d_in[14];

  char* ws = (char*)d_ws;
  int* cidxp = (int*)(ws + OFF_CIDX);
  int* nidxp = (int*)(ws + OFF_NIDX);
  float* ss   = (float*)(ws + OFF_SS);
  float* psum = (float*)(ws + OFF_PSUM);
  float* psqr = (float*)(ws + OFF_PSQR);
  float* gmax = (float*)(ws + OFF_GMAX);
  float* gmin = (float*)(ws + OFF_GMIN);
  unsigned short* fT = (unsigned short*)(ws + OFF_FT);
  unsigned short* y1 = (unsigned short*)(ws + OFF_Y1);

  float* out         = (float*)d_out;
  float* centers_out = out + (size_t)8 * 256 * 1024;
  float* cond_out    = centers_out + (size_t)8 * 3 * 1024;

  const bool big = (ws_size >= NEED_BIG);

  fps_kernel<<<8, 256, 0, stream>>>(coords, cidxp, centers_out);
  featT_kernel<<<dim3(128, 8), 256, 0, stream>>>(feat, fT);
  bq_kernel<<<dim3(256, 8), 256, 0, stream>>>(coords, cidxp, nidxp);

  fused_kernel<1, false, false><<<4096, 256, 0, stream>>>(
      fT, coords, cidxp, nidxp, y1, ss, w0, b0, w1, b1, w2, b2, psum, psqr, gmax, gmin);
  ss_kernel<128><<<128, 256, 0, stream>>>(psum, psqr, ga0, be0, ss);

  if (big) {
    fused_kernel<2, false, true><<<4096, 256, 0, stream>>>(
        fT, coords, cidxp, nidxp, y1, ss, w0, b0, w1, b1, w2, b2, psum, psqr, gmax, gmin);
  } else {
    fused_kernel<2, false, false><<<4096, 256, 0, stream>>>(
        fT, coords, cidxp, nidxp, y1, ss, w0, b0, w1, b1, w2, b2, psum, psqr, gmax, gmin);
  }
  ss_kernel<128><<<128, 256, 0, stream>>>(psum, psqr, ga1, be1, ss + 256);

  if (big) {
    fused_kernel<3, true, false><<<4096, 256, 0, stream>>>(
        fT, coords, cidxp, nidxp, y1, ss, w0, b0, w1, b1, w2, b2, psum, psqr, gmax, gmin);
  } else {
    fused_kernel<3, false, false><<<4096, 256, 0, stream>>>(
        fT, coords, cidxp, nidxp, y1, ss, w0, b0, w1, b1, w2, b2, psum, psqr, gmax, gmin);
  }
  ss_kernel<256><<<256, 256, 0, stream>>>(psum, psqr, ga2, be2, ss + 512);

  final_kernel<<<256, 256, 0, stream>>>(gmax, gmin, ss + 512, out);
  cond_kernel<<<1, 512, 0, stream>>>(cond, cond_out);
}

// Round 10
// 1370.141 us; speedup vs baseline: 1.0436x; 1.0436x over previous
//
#include <hip/hip_runtime.h>

#define NB    8
#define NPTS  8192
#define NCTR  1024
#define KNN   64
#define NGRP  8192
#define SAMP  524288
#define EPSB  1e-5f

// ---- ws layout (bytes), total SMALL = ~31.5 MB, BIG = ~166 MB ----
#define OFF_CIDX 0ull
#define OFF_NIDX 32768ull
#define OFF_SS   2129920ull
#define OFF_PSUM 2134016ull
#define OFF_PSQR 4231168ull
#define OFF_GMAX 6328320ull
#define OFF_GMIN 14716928ull
#define OFF_FT   23105536ull
#define OFF_Y1   31494144ull
#define NEED_BIG 165711872ull

typedef unsigned short ushort8 __attribute__((ext_vector_type(8)));
typedef short short8v __attribute__((ext_vector_type(8)));
typedef float f32x4 __attribute__((ext_vector_type(4)));

__device__ __forceinline__ unsigned short f2b(float f) {
  unsigned int u = __builtin_bit_cast(unsigned int, f);
  u += 0x7fffu + ((u >> 16) & 1u);
  return (unsigned short)(u >> 16);
}
__device__ __forceinline__ float b2f(unsigned short s) {
  unsigned int u = ((unsigned int)s) << 16;
  return __builtin_bit_cast(float, u);
}

// DPP-assisted max step: r = max(r, dpp_move(r)) ; bound_ctrl=1 -> invalid src reads 0.0
template <int CTRL>
__device__ __forceinline__ float dppmax(float x) {
  int m = __builtin_amdgcn_update_dpp(0, __builtin_bit_cast(int, x), CTRL, 0xf, 0xf, true);
  return fmaxf(x, __builtin_bit_cast(float, m));
}

// ---------------- FPS: 8 waves (2/SIMD for latency hiding), DPP wave-max + ballot ----------------
// Thread t owns contiguous points [t*16, t*16+16) -> lane order == index order, so
// ballot+ctz after the max reduce picks the smallest index (numpy first-occurrence).
// Inter-wave: u64 pack (bits(dist)<<32)|~idx; max == (max dist, then min idx).
__global__ __launch_bounds__(512) void fps_kernel(const float* __restrict__ coords,
                                                  int* __restrict__ cidx,
                                                  float* __restrict__ centers_out) {
  const int b = blockIdx.x;
  const int t = threadIdx.x;
  const int wid = t >> 6, lane = t & 63;
  __shared__ float4 sc4[NPTS];                 // 128 KB packed coords
  __shared__ unsigned long long red[2][8];
  const float* cb = coords + (size_t)b * 3 * NPTS;
  for (int i = t; i < NPTS; i += 512)
    sc4[i] = make_float4(cb[i], cb[NPTS + i], cb[2 * NPTS + i], 0.f);
  __syncthreads();
  constexpr int PT = NPTS / 512;  // 16, contiguous per thread
  float px[PT], py[PT], pz[PT], dst[PT];
#pragma unroll
  for (int i = 0; i < PT; ++i) {
    int p = t * PT + i;
    px[i] = cb[p]; py[i] = cb[NPTS + p]; pz[i] = cb[2 * NPTS + p];
    dst[i] = 1e10f;
  }
  int cur = 0;
  float4 c0 = sc4[0];
  float cx = c0.x, cy = c0.y, cz = c0.z;
  int parity = 0;
  for (int s = 0; s < NCTR; ++s) {
    if (t == 0) {
      cidx[b * NCTR + s] = cur;
      centers_out[(b * 3 + 0) * NCTR + s] = cx;
      centers_out[(b * 3 + 1) * NCTR + s] = cy;
      centers_out[(b * 3 + 2) * NCTR + s] = cz;
    }
    float bv = -1.0f; int bi = 0;
#pragma unroll
    for (int i = 0; i < PT; ++i) {
      // exact numpy f32 order: ((dx*dx + dy*dy) + dz*dz), no fma contraction
      float dx = __fsub_rn(px[i], cx);
      float dy = __fsub_rn(py[i], cy);
      float dz = __fsub_rn(pz[i], cz);
      float d2 = __fadd_rn(__fadd_rn(__fmul_rn(dx, dx), __fmul_rn(dy, dy)), __fmul_rn(dz, dz));
      float nd = fminf(dst[i], d2);
      dst[i] = nd;
      if (nd > bv) { bv = nd; bi = t * PT + i; }   // ascending i -> first occurrence
    }
    float r = bv;
    r = dppmax<0x111>(r);
    r = dppmax<0x112>(r);
    r = dppmax<0x114>(r);
    r = dppmax<0x118>(r);
    r = dppmax<0x142>(r);
    r = dppmax<0x143>(r);
    float wm = __builtin_bit_cast(float,
        __builtin_amdgcn_readlane(__builtin_bit_cast(int, r), 63));
    unsigned long long mask = __ballot(bv == wm);
    int widx = __shfl(bi, (int)__builtin_ctzll(mask));  // lowest lane == smallest index
    if (lane == 0)
      red[parity][wid] =
          ((unsigned long long)__builtin_bit_cast(unsigned int, wm) << 32) |
          (unsigned long long)(~(unsigned int)widx);
    __syncthreads();
    unsigned long long best = red[parity][0];
#pragma unroll
    for (int k = 1; k < 8; ++k) {
      unsigned long long o = red[parity][k];
      best = (o > best) ? o : best;
    }
    cur = (int)(~(unsigned int)best);
    float4 cc = sc4[cur];                       // single b128 LDS broadcast
    cx = cc.x; cy = cc.y; cz = cc.z;
    parity ^= 1;
  }
}

// ---------------- feat transpose to [B][N][64] bf16 ----------------
__global__ __launch_bounds__(256) void featT_kernel(const float* __restrict__ feat,
                                                    unsigned short* __restrict__ fT) {
  int b  = blockIdx.y;
  int j  = blockIdx.x * 64 + (threadIdx.x & 63);
  int cg = threadIdx.x >> 6;
  ushort8 v0, v1;
#pragma unroll
  for (int cc = 0; cc < 8; ++cc)
    v0[cc] = f2b(feat[((size_t)b * 64 + cg * 16 + cc) * NPTS + j]);
#pragma unroll
  for (int cc = 0; cc < 8; ++cc)
    v1[cc] = f2b(feat[((size_t)b * 64 + cg * 16 + 8 + cc) * NPTS + j]);
  unsigned short* dst = fT + ((size_t)b * NPTS + j) * 64 + cg * 16;
  *(ushort8*)dst = v0;
  *(ushort8*)(dst + 8) = v1;
}

// ---------------- ball query: wave per center, stream coords from L2 ----------------
__global__ __launch_bounds__(256) void bq_kernel(const float* __restrict__ coords,
                                                 const int* __restrict__ cidx,
                                                 int* __restrict__ nidx) {
  const int b = blockIdx.y;
  const int w = threadIdx.x >> 6, lane = threadIdx.x & 63;
  const int m = blockIdx.x * 4 + w;
  const float* cb = coords + (size_t)b * 3 * NPTS;
  const int cen = cidx[b * NCTR + m];
  const float cx = cb[cen], cy = cb[NPTS + cen], cz = cb[2 * NPTS + cen];
  int* outp = nidx + ((size_t)b * NCTR + m) * KNN;
  const float RR = (float)(0.2 * 0.2);   // exact f64->f32 like numpy
  int found = 0, first = -1;
  for (int chunk = 0; chunk < NPTS / 64 && found < KNN; ++chunk) {
    int p = chunk * 64 + lane;
    float dx = __fsub_rn(cx, cb[p]);
    float dy = __fsub_rn(cy, cb[NPTS + p]);
    float dz = __fsub_rn(cz, cb[2 * NPTS + p]);
    float d2 = __fadd_rn(__fadd_rn(__fmul_rn(dx, dx), __fmul_rn(dy, dy)), __fmul_rn(dz, dz));
    bool pred = d2 < RR;
    unsigned long long mask = __ballot(pred);
    if (pred) {
      int rank = __popcll(mask & ((1ull << lane) - 1ull));
      int slot = found + rank;
      if (slot < KNN) outp[slot] = p;
    }
    if (first < 0 && mask != 0ull) first = chunk * 64 + __builtin_ctzll(mask);
    found += __popcll(mask);
  }
  if (found < KNN) {
    int f = (first < 0) ? 0 : first;
    if (lane >= found) outp[lane] = f;
  }
}

// ---------------- fused conv chain: 512 thr, 8 waves, 2 waves per group (R8 + race fixes) ----------------
// Wave wv = group*2 + hp; the pair shares one group's X tile; each wave computes
// output channels o in [hp*64, hp*64+64). 2 waves/SIMD hide staging latency.
// NL=1: conv0 -> stats0.  NL=2: conv0->bn0->conv1 -> stats1 (+y1 if WRITEY1).
// NL=3: (READY1 ? y1 : conv0->bn0->conv1) -> bn1 -> conv2 -> per-group max/min + stats2.
template <int NL, bool READY1, bool WRITEY1>
__global__ __launch_bounds__(512) void fused_kernel(
    const unsigned short* __restrict__ fT, const float* __restrict__ coords,
    const int* __restrict__ cidx, const int* __restrict__ nidx,
    unsigned short* __restrict__ y1, const float* __restrict__ ss,
    const float* __restrict__ w0, const float* __restrict__ b0,
    const float* __restrict__ w1, const float* __restrict__ b1,
    const float* __restrict__ w2, const float* __restrict__ b2,
    float* __restrict__ psum, float* __restrict__ psqr,
    float* __restrict__ gmax, float* __restrict__ gmin) {
  __shared__ __align__(16) unsigned short Xs[4 * 64 * 128];   // 64 KB
  __shared__ __align__(16) unsigned short Wbuf[128 * 128];    // 32 KB
  __shared__ float s_bias[128];
  __shared__ float s_sc0[128], s_sh0[128], s_sc1[128], s_sh1[128];
  __shared__ float s_rs[8][64], s_rq[8][64];

  const int t = threadIdx.x;
  const int wv = t >> 6, lane = t & 63;
  const int wg = wv >> 1;          // group 0..3
  const int hp = wv & 1;           // output-half parity
  const int r16 = lane & 15, kg = lane >> 4;
  const int g = blockIdx.x * 4 + wg;
  const int bb_ = g >> 10;
  const int rsw = lane & 7;
  unsigned short* xrow = &Xs[(wg * 64 + lane) * 128];

  if constexpr (NL >= 2 && !READY1) {
    if (t < 128) { s_sc0[t] = ss[t]; s_sh0[t] = ss[128 + t]; }
  }
  if constexpr (NL >= 3) {
    if (t < 128) { s_sc1[t] = ss[256 + t]; s_sh1[t] = ss[384 + t]; }
  }

  auto stageW = [&](const float* w, const float* bia, bool remap0, int oh) {
    for (int e = t; e < 128 * 128; e += 512) {
      int o = e >> 7, c = e & 127;
      float v;
      if (remap0) {
        int lc = (c < 64) ? (c + 3) : ((c < 67) ? (c - 64) : -1);
        v = (lc >= 0) ? w[o * 67 + lc] : 0.f;
      } else {
        v = w[((size_t)(oh * 128 + o)) * 128 + c];
      }
      Wbuf[(o << 7) + ((((c >> 3) ^ (o & 7)) << 3) | (c & 7))] = f2b(v);
    }
    if (t < 128) s_bias[t] = bia[oh * 128 + t];
  };

  // per-wave partials over its 4 nt tiles (channels hp*64 + k*16 + r16)
  auto statsOut = [&](float (&sv4)[4], float (&sq4)[4], int coff) {
#pragma unroll
    for (int k = 0; k < 4; ++k) {
      sv4[k] += __shfl_xor(sv4[k], 16); sv4[k] += __shfl_xor(sv4[k], 32);
      sq4[k] += __shfl_xor(sq4[k], 16); sq4[k] += __shfl_xor(sq4[k], 32);
    }
    if (lane < 16) {
#pragma unroll
      for (int k = 0; k < 4; ++k) {
        s_rs[wv][k * 16 + lane] = sv4[k];
        s_rq[wv][k * 16 + lane] = sq4[k];
      }
    }
    __syncthreads();
    if (t < 128) {
      int hp2 = t >> 6, cl = t & 63;
      float sB = s_rs[0 + hp2][cl] + s_rs[2 + hp2][cl] + s_rs[4 + hp2][cl] + s_rs[6 + hp2][cl];
      float qB = s_rq[0 + hp2][cl] + s_rq[2 + hp2][cl] + s_rq[4 + hp2][cl] + s_rq[6 + hp2][cl];
      psum[(size_t)blockIdx.x * 256 + coff + t] = sB;
      psqr[(size_t)blockIdx.x * 256 + coff + t] = qB;
    }
  };

  short8v a[4][4];

  if constexpr (!READY1) {
    if (hp == 0) {  // even wave stages its group's X0 (lane = row)
      int j = nidx[(size_t)g * KNN + lane];
      int cen = cidx[g];
      const unsigned short* fr = fT + ((size_t)bb_ * NPTS + j) * 64;
#pragma unroll
      for (int ch = 0; ch < 8; ++ch)
        *(ushort8*)(xrow + ((ch ^ rsw) << 3)) = *(const ushort8*)(fr + ch * 8);
      const float* cb = coords + (size_t)bb_ * 3 * NPTS;
      float rx = __fsub_rn(cb[j], cb[cen]);
      float ry = __fsub_rn(cb[NPTS + j], cb[NPTS + cen]);
      float rz = __fsub_rn(cb[2 * NPTS + j], cb[2 * NPTS + cen]);
      ushort8 rv = {f2b(rx), f2b(ry), f2b(rz), 0, 0, 0, 0, 0};
      *(ushort8*)(xrow + ((8 ^ rsw) << 3)) = rv;
      ushort8 zz = {0, 0, 0, 0, 0, 0, 0, 0};
#pragma unroll
      for (int ch = 9; ch < 16; ++ch)
        *(ushort8*)(xrow + ((ch ^ rsw) << 3)) = zz;
    }
    stageW(w0, b0, true, 0);
    __syncthreads();

    // ---- layer 0 ----
#pragma unroll
    for (int st = 0; st < 4; ++st) {
      int row = st * 16 + r16;
#pragma unroll
      for (int ks = 0; ks < 3; ++ks)
        a[st][ks] = __builtin_bit_cast(short8v,
            *(const ushort8*)&Xs[(wg * 64 + row) * 128 + (((ks * 4 + kg) ^ (row & 7)) << 3)]);
    }
    if constexpr (NL >= 2) __syncthreads();   // race fix: all a-loads before epilogue Xs writes
    {
      float sv4[4], sq4[4];
#pragma unroll
      for (int k = 0; k < 4; ++k) { sv4[k] = 0.f; sq4[k] = 0.f; }
#pragma unroll
      for (int k = 0; k < 4; ++k) {
        int o = hp * 64 + k * 16 + r16;
        short8v wb[3];
#pragma unroll
        for (int ks = 0; ks < 3; ++ks)
          wb[ks] = __builtin_bit_cast(short8v,
              *(const ushort8*)&Wbuf[(o << 7) + (((ks * 4 + kg) ^ (o & 7)) << 3)]);
        float bia = s_bias[o];
        float sc = 0.f, sh = 0.f;
        if constexpr (NL >= 2) { sc = s_sc0[o]; sh = s_sh0[o]; }
#pragma unroll
        for (int st = 0; st < 4; ++st) {
          f32x4 acc = {0.f, 0.f, 0.f, 0.f};
#pragma unroll
          for (int ks = 0; ks < 3; ++ks)
            acc = __builtin_amdgcn_mfma_f32_16x16x32_bf16(a[st][ks], wb[ks], acc, 0, 0, 0);
#pragma unroll
          for (int r = 0; r < 4; ++r) {
            float v = acc[r] + bia;
            if constexpr (NL == 1) {
              sv4[k] += v; sq4[k] = fmaf(v, v, sq4[k]);
            } else {
              float x = fmaxf(fmaf(v, sc, sh), 0.f);
              int row = st * 16 + kg * 4 + r;
              Xs[(wg * 64 + row) * 128 + ((((o >> 3) ^ (row & 7)) << 3) | (o & 7))] = f2b(x);
            }
          }
        }
      }
      if constexpr (NL == 1) { statsOut(sv4, sq4, 0); return; }
    }

    // ---- layer 1 ----
    if constexpr (NL >= 2) {
      __syncthreads();
      stageW(w1, b1, false, 0);
      __syncthreads();
#pragma unroll
      for (int st = 0; st < 4; ++st) {
        int row = st * 16 + r16;
#pragma unroll
        for (int ks = 0; ks < 4; ++ks)
          a[st][ks] = __builtin_bit_cast(short8v,
              *(const ushort8*)&Xs[(wg * 64 + row) * 128 + (((ks * 4 + kg) ^ (row & 7)) << 3)]);
      }
      if constexpr (NL >= 3) __syncthreads();   // race fix: a-loads before bn1 Xs writes
      float sv4[4], sq4[4];
#pragma unroll
      for (int k = 0; k < 4; ++k) { sv4[k] = 0.f; sq4[k] = 0.f; }
#pragma unroll
      for (int k = 0; k < 4; ++k) {
        int o = hp * 64 + k * 16 + r16;
        short8v wb[4];
#pragma unroll
        for (int ks = 0; ks < 4; ++ks)
          wb[ks] = __builtin_bit_cast(short8v,
              *(const ushort8*)&Wbuf[(o << 7) + (((ks * 4 + kg) ^ (o & 7)) << 3)]);
        float bia = s_bias[o];
        float sc = 0.f, sh = 0.f;
        if constexpr (NL >= 3) { sc = s_sc1[o]; sh = s_sh1[o]; }
#pragma unroll
        for (int st = 0; st < 4; ++st) {
          f32x4 acc = {0.f, 0.f, 0.f, 0.f};
#pragma unroll
          for (int ks = 0; ks < 4; ++ks)
            acc = __builtin_amdgcn_mfma_f32_16x16x32_bf16(a[st][ks], wb[ks], acc, 0, 0, 0);
#pragma unroll
          for (int r = 0; r < 4; ++r) {
            float v = acc[r] + bia;
            int row = st * 16 + kg * 4 + r;
            if constexpr (NL == 2) {
              sv4[k] += v; sq4[k] = fmaf(v, v, sq4[k]);
              if constexpr (WRITEY1)
                y1[((size_t)g * 64 + row) * 128 + o] = f2b(v);
            } else {
              float x = fmaxf(fmaf(v, sc, sh), 0.f);
              Xs[(wg * 64 + row) * 128 + ((((o >> 3) ^ (row & 7)) << 3) | (o & 7))] = f2b(x);
            }
          }
        }
      }
      if constexpr (NL == 2) { statsOut(sv4, sq4, 0); return; }
    }
  } else {
    // READY1 (NL==3): even wave stages X2 = relu(bn1(y1)) for its group
    __syncthreads();   // s_sc1/s_sh1 ready
    if (hp == 0) {
      const unsigned short* yr = y1 + ((size_t)g * 64 + lane) * 128;
#pragma unroll
      for (int ch = 0; ch < 16; ++ch) {
        ushort8 vv = *(const ushort8*)(yr + ch * 8);
        ushort8 ov;
#pragma unroll
        for (int jj = 0; jj < 8; ++jj) {
          int c = ch * 8 + jj;
          ov[jj] = f2b(fmaxf(fmaf(b2f(vv[jj]), s_sc1[c], s_sh1[c]), 0.f));
        }
        *(ushort8*)(xrow + ((ch ^ rsw) << 3)) = ov;
      }
    }
  }

  // ---- layer 2 (NL==3): two output halves, max/min + stats ----
  if constexpr (NL == 3) {
    __syncthreads();   // X2 tile complete (staged/written by partner waves)
#pragma unroll
    for (int st = 0; st < 4; ++st) {
      int row = st * 16 + r16;
#pragma unroll
      for (int ks = 0; ks < 4; ++ks)
        a[st][ks] = __builtin_bit_cast(short8v,
            *(const ushort8*)&Xs[(wg * 64 + row) * 128 + (((ks * 4 + kg) ^ (row & 7)) << 3)]);
    }
    for (int h = 0; h < 2; ++h) {
      __syncthreads();
      stageW(w2, b2, false, h);
      __syncthreads();
      float mx4[4], mn4[4], sv4[4], sq4[4];
#pragma unroll
      for (int k = 0; k < 4; ++k) { mx4[k] = -1e30f; mn4[k] = 1e30f; sv4[k] = 0.f; sq4[k] = 0.f; }
#pragma unroll
      for (int k = 0; k < 4; ++k) {
        int o = hp * 64 + k * 16 + r16;
        short8v wb[4];
#pragma unroll
        for (int ks = 0; ks < 4; ++ks)
          wb[ks] = __builtin_bit_cast(short8v,
              *(const ushort8*)&Wbuf[(o << 7) + (((ks * 4 + kg) ^ (o & 7)) << 3)]);
        float bia = s_bias[o];
#pragma unroll
        for (int st = 0; st < 4; ++st) {
          f32x4 acc = {0.f, 0.f, 0.f, 0.f};
#pragma unroll
          for (int ks = 0; ks < 4; ++ks)
            acc = __builtin_amdgcn_mfma_f32_16x16x32_bf16(a[st][ks], wb[ks], acc, 0, 0, 0);
#pragma unroll
          for (int r = 0; r < 4; ++r) {
            float v = acc[r] + bia;
            mx4[k] = fmaxf(mx4[k], v); mn4[k] = fminf(mn4[k], v);
            sv4[k] += v; sq4[k] = fmaf(v, v, sq4[k]);
          }
        }
      }
#pragma unroll
      for (int k = 0; k < 4; ++k) {
        mx4[k] = fmaxf(mx4[k], __shfl_xor(mx4[k], 16));
        mx4[k] = fmaxf(mx4[k], __shfl_xor(mx4[k], 32));
        mn4[k] = fminf(mn4[k], __shfl_xor(mn4[k], 16));
        mn4[k] = fminf(mn4[k], __shfl_xor(mn4[k], 32));
      }
      if (lane < 16) {
#pragma unroll
        for (int k = 0; k < 4; ++k) {
          gmax[(size_t)g * 256 + h * 128 + hp * 64 + k * 16 + lane] = mx4[k];
          gmin[(size_t)g * 256 + h * 128 + hp * 64 + k * 16 + lane] = mn4[k];
        }
      }
      statsOut(sv4, sq4, h * 128);
    }
  }
}

// ---------------- stats finalize (2048 partial rows) ----------------
template <int O>
__global__ __launch_bounds__(256) void ss_kernel(const float* __restrict__ psum,
                                                 const float* __restrict__ psqr,
                                                 const float* __restrict__ gamma,
                                                 const float* __restrict__ beta,
                                                 float* __restrict__ ss_out) {
  int c = blockIdx.x;
  int t = threadIdx.x;
  float s = 0.f, q = 0.f;
  for (int i = t; i < 2048; i += 256) {
    s += psum[(size_t)i * 256 + c];
    q += psqr[(size_t)i * 256 + c];
  }
  int lane = t & 63, wid = t >> 6;
#pragma unroll
  for (int off = 32; off > 0; off >>= 1) { s += __shfl_down(s, off); q += __shfl_down(q, off); }
  __shared__ float rv[4], rqv[4];
  if (lane == 0) { rv[wid] = s; rqv[wid] = q; }
  __syncthreads();
  if (t == 0) {
    s = rv[0] + rv[1] + rv[2] + rv[3];
    q = rqv[0] + rqv[1] + rqv[2] + rqv[3];
    const float inv = 1.0f / (float)SAMP;
    float mu = s * inv;
    float var = fmaxf(q * inv - mu * mu, 0.f);
    float rs = 1.0f / sqrtf(var + EPSB);
    float sc = gamma[c] * rs;
    ss_out[c] = sc;
    ss_out[O + c] = beta[c] - mu * sc;
  }
}

// ---------------- final: out = relu(max(sc*mx+sh, sc*mn+sh)), LDS transpose ----------------
__global__ __launch_bounds__(256) void final_kernel(const float* __restrict__ gmax,
                                                    const float* __restrict__ gmin,
                                                    const float* __restrict__ ss2,
                                                    float* __restrict__ out) {
  int b = blockIdx.x >> 5, mt = blockIdx.x & 31;
  int t = threadIdx.x;
  __shared__ float tile[32][257];
  float sc = ss2[t], sh = ss2[256 + t];
  size_t base = ((size_t)b * 1024 + mt * 32) * 256;
#pragma unroll
  for (int r = 0; r < 32; ++r) {
    float A = fmaf(gmax[base + r * 256 + t], sc, sh);
    float C = fmaf(gmin[base + r * 256 + t], sc, sh);
    tile[r][t] = fmaxf(fmaxf(A, C), 0.f);
  }
  __syncthreads();
  for (int i = t; i < 8192; i += 256) {
    int o = i >> 5, ml = i & 31;
    out[((size_t)b * 256 + o) * 1024 + mt * 32 + ml] = tile[ml][o];
  }
}

__global__ void cond_kernel(const float* __restrict__ cond, float* __restrict__ dst) {
  dst[threadIdx.x] = cond[threadIdx.x];
}

extern "C" void kernel_launch(void* const* d_in, const int* in_sizes, int n_in,
                              void* d_out, int out_size, void* d_ws, size_t ws_size,
                              hipStream_t stream) {
  const float* feat   = (const float*)d_in[0];
  const float* coords = (const float*)d_in[1];
  const float* cond   = (const float*)d_in[2];
  const float* w0  = (const float*)d_in[3];
  const float* b0  = (const float*)d_in[4];
  const float* ga0 = (const float*)d_in[5];
  const float* be0 = (const float*)d_in[6];
  const float* w1  = (const float*)d_in[7];
  const float* b1  = (const float*)d_in[8];
  const float* ga1 = (const float*)d_in[9];
  const float* be1 = (const float*)d_in[10];
  const float* w2  = (const float*)d_in[11];
  const float* b2  = (const float*)d_in[12];
  const float* ga2 = (const float*)d_in[13];
  const float* be2 = (const float*)d_in[14];

  char* ws = (char*)d_ws;
  int* cidxp = (int*)(ws + OFF_CIDX);
  int* nidxp = (int*)(ws + OFF_NIDX);
  float* ss   = (float*)(ws + OFF_SS);
  float* psum = (float*)(ws + OFF_PSUM);
  float* psqr = (float*)(ws + OFF_PSQR);
  float* gmax = (float*)(ws + OFF_GMAX);
  float* gmin = (float*)(ws + OFF_GMIN);
  unsigned short* fT = (unsigned short*)(ws + OFF_FT);
  unsigned short* y1 = (unsigned short*)(ws + OFF_Y1);

  float* out         = (float*)d_out;
  float* centers_out = out + (size_t)8 * 256 * 1024;
  float* cond_out    = centers_out + (size_t)8 * 3 * 1024;

  const bool big = (ws_size >= NEED_BIG);

  fps_kernel<<<8, 512, 0, stream>>>(coords, cidxp, centers_out);
  featT_kernel<<<dim3(128, 8), 256, 0, stream>>>(feat, fT);
  bq_kernel<<<dim3(256, 8), 256, 0, stream>>>(coords, cidxp, nidxp);

  fused_kernel<1, false, false><<<2048, 512, 0, stream>>>(
      fT, coords, cidxp, nidxp, y1, ss, w0, b0, w1, b1, w2, b2, psum, psqr, gmax, gmin);
  ss_kernel<128><<<128, 256, 0, stream>>>(psum, psqr, ga0, be0, ss);

  if (big) {
    fused_kernel<2, false, true><<<2048, 512, 0, stream>>>(
        fT, coords, cidxp, nidxp, y1, ss, w0, b0, w1, b1, w2, b2, psum, psqr, gmax, gmin);
  } else {
    fused_kernel<2, false, false><<<2048, 512, 0, stream>>>(
        fT, coords, cidxp, nidxp, y1, ss, w0, b0, w1, b1, w2, b2, psum, psqr, gmax, gmin);
  }
  ss_kernel<128><<<128, 256, 0, stream>>>(psum, psqr, ga1, be1, ss + 256);

  if (big) {
    fused_kernel<3, true, false><<<2048, 512, 0, stream>>>(
        fT, coords, cidxp, nidxp, y1, ss, w0, b0, w1, b1, w2, b2, psum, psqr, gmax, gmin);
  } else {
    fused_kernel<3, false, false><<<2048, 512, 0, stream>>>(
        fT, coords, cidxp, nidxp, y1, ss, w0, b0, w1, b1, w2, b2, psum, psqr, gmax, gmin);
  }
  ss_kernel<256><<<256, 256, 0, stream>>>(psum, psqr, ga2, be2, ss + 512);

  final_kernel<<<256, 256, 0, stream>>>(gmax, gmin, ss + 512, out);
  cond_kernel<<<1, 512, 0, stream>>>(cond, cond_out);
}

// Round 11
// 1351.179 us; speedup vs baseline: 1.0582x; 1.0140x over previous
//
#include <hip/hip_runtime.h>

#define NB    8
#define NPTS  8192
#define NCTR  1024
#define KNN   64
#define NGRP  8192
#define SAMP  524288
#define EPSB  1e-5f

// ---- ws layout (bytes), total SMALL = ~31.5 MB, BIG = ~166 MB ----
#define OFF_CIDX 0ull
#define OFF_NIDX 32768ull
#define OFF_SS   2129920ull
#define OFF_PSUM 2134016ull
#define OFF_PSQR 4231168ull
#define OFF_GMAX 6328320ull
#define OFF_GMIN 14716928ull
#define OFF_FT   23105536ull
#define OFF_Y1   31494144ull
#define NEED_BIG 165711872ull

typedef unsigned short ushort8 __attribute__((ext_vector_type(8)));
typedef short short8v __attribute__((ext_vector_type(8)));
typedef float f32x4 __attribute__((ext_vector_type(4)));

__device__ __forceinline__ unsigned short f2b(float f) {
  unsigned int u = __builtin_bit_cast(unsigned int, f);
  u += 0x7fffu + ((u >> 16) & 1u);
  return (unsigned short)(u >> 16);
}
__device__ __forceinline__ float b2f(unsigned short s) {
  unsigned int u = ((unsigned int)s) << 16;
  return __builtin_bit_cast(float, u);
}

// DPP-assisted max step: r = max(r, dpp_move(r)) ; bound_ctrl=1 -> invalid src reads 0.0
template <int CTRL>
__device__ __forceinline__ float dppmax(float x) {
  int m = __builtin_amdgcn_update_dpp(0, __builtin_bit_cast(int, x), CTRL, 0xf, 0xf, true);
  return fmaxf(x, __builtin_bit_cast(float, m));
}

// ---------------- FPS: 4 waves, 4-chain in-thread argmax, DPP wave-max + ballot ----------------
// Thread t owns contiguous points [t*32, t*32+32), split into 4 chains of 8
// contiguous points. Chain merge a.v>=b.v?a:b with left indices < right indices
// == first-occurrence tie-break; ballot+ctz picks lowest lane == smallest index
// (numpy argmax exactly). Inter-wave: u64 pack (bits(dist)<<32)|~idx.
__global__ __launch_bounds__(256) void fps_kernel(const float* __restrict__ coords,
                                                  int* __restrict__ cidx,
                                                  float* __restrict__ centers_out) {
  const int b = blockIdx.x;
  const int t = threadIdx.x;
  const int wid = t >> 6, lane = t & 63;
  __shared__ float4 sc4[NPTS];                 // 128 KB packed coords
  __shared__ unsigned long long red[2][4];
  const float* cb = coords + (size_t)b * 3 * NPTS;
  for (int i = t; i < NPTS; i += 256)
    sc4[i] = make_float4(cb[i], cb[NPTS + i], cb[2 * NPTS + i], 0.f);
  __syncthreads();
  constexpr int PT = NPTS / 256;  // 32, contiguous per thread
  float px[PT], py[PT], pz[PT], dst[PT];
#pragma unroll
  for (int i = 0; i < PT; ++i) {
    int p = t * PT + i;
    px[i] = cb[p]; py[i] = cb[NPTS + p]; pz[i] = cb[2 * NPTS + p];
    dst[i] = 1e10f;
  }
  int cur = 0;
  float4 c0 = sc4[0];
  float cx = c0.x, cy = c0.y, cz = c0.z;
  int parity = 0;
  for (int s = 0; s < NCTR; ++s) {
    if (t == 0) {
      cidx[b * NCTR + s] = cur;
      centers_out[(b * 3 + 0) * NCTR + s] = cx;
      centers_out[(b * 3 + 1) * NCTR + s] = cy;
      centers_out[(b * 3 + 2) * NCTR + s] = cz;
    }
    // 4 independent argmax chains over contiguous 8-point sub-ranges
    float bvc[4] = {-1.0f, -1.0f, -1.0f, -1.0f};
    int   bic[4] = {0, 0, 0, 0};
#pragma unroll
    for (int c = 0; c < 4; ++c) {
#pragma unroll
      for (int i2 = 0; i2 < 8; ++i2) {
        int i = c * 8 + i2;
        // exact numpy f32 order: ((dx*dx + dy*dy) + dz*dz), no fma contraction
        float dx = __fsub_rn(px[i], cx);
        float dy = __fsub_rn(py[i], cy);
        float dz = __fsub_rn(pz[i], cz);
        float d2 = __fadd_rn(__fadd_rn(__fmul_rn(dx, dx), __fmul_rn(dy, dy)), __fmul_rn(dz, dz));
        float nd = fminf(dst[i], d2);
        dst[i] = nd;
        if (nd > bvc[c]) { bvc[c] = nd; bic[c] = t * PT + i; }  // ascending i
      }
    }
    // merge: left chain's indices all smaller -> >= keeps first occurrence
    float vA = (bvc[0] >= bvc[1]) ? bvc[0] : bvc[1];
    int   iA = (bvc[0] >= bvc[1]) ? bic[0] : bic[1];
    float vB = (bvc[2] >= bvc[3]) ? bvc[2] : bvc[3];
    int   iB = (bvc[2] >= bvc[3]) ? bic[2] : bic[3];
    float bv = (vA >= vB) ? vA : vB;
    int   bi = (vA >= vB) ? iA : iB;
    // in-wave max via DPP: row_shr 1/2/4/8 then row_bcast15/31; lane 63 holds wave max
    float r = bv;
    r = dppmax<0x111>(r);
    r = dppmax<0x112>(r);
    r = dppmax<0x114>(r);
    r = dppmax<0x118>(r);
    r = dppmax<0x142>(r);
    r = dppmax<0x143>(r);
    float wm = __builtin_bit_cast(float,
        __builtin_amdgcn_readlane(__builtin_bit_cast(int, r), 63));
    unsigned long long mask = __ballot(bv == wm);
    int widx = __shfl(bi, (int)__builtin_ctzll(mask));  // lowest lane == smallest index
    if (lane == 0)
      red[parity][wid] =
          ((unsigned long long)__builtin_bit_cast(unsigned int, wm) << 32) |
          (unsigned long long)(~(unsigned int)widx);
    __syncthreads();
    unsigned long long best = red[parity][0];
#pragma unroll
    for (int k = 1; k < 4; ++k) {
      unsigned long long o = red[parity][k];
      best = (o > best) ? o : best;
    }
    cur = (int)(~(unsigned int)best);
    float4 cc = sc4[cur];                       // single b128 LDS broadcast
    cx = cc.x; cy = cc.y; cz = cc.z;
    parity ^= 1;
  }
}

// ---------------- feat transpose to [B][N][64] bf16 ----------------
__global__ __launch_bounds__(256) void featT_kernel(const float* __restrict__ feat,
                                                    unsigned short* __restrict__ fT) {
  int b  = blockIdx.y;
  int j  = blockIdx.x * 64 + (threadIdx.x & 63);
  int cg = threadIdx.x >> 6;
  ushort8 v0, v1;
#pragma unroll
  for (int cc = 0; cc < 8; ++cc)
    v0[cc] = f2b(feat[((size_t)b * 64 + cg * 16 + cc) * NPTS + j]);
#pragma unroll
  for (int cc = 0; cc < 8; ++cc)
    v1[cc] = f2b(feat[((size_t)b * 64 + cg * 16 + 8 + cc) * NPTS + j]);
  unsigned short* dst = fT + ((size_t)b * NPTS + j) * 64 + cg * 16;
  *(ushort8*)dst = v0;
  *(ushort8*)(dst + 8) = v1;
}

// ---------------- ball query: wave per center, stream coords from L2 ----------------
__global__ __launch_bounds__(256) void bq_kernel(const float* __restrict__ coords,
                                                 const int* __restrict__ cidx,
                                                 int* __restrict__ nidx) {
  const int b = blockIdx.y;
  const int w = threadIdx.x >> 6, lane = threadIdx.x & 63;
  const int m = blockIdx.x * 4 + w;
  const float* cb = coords + (size_t)b * 3 * NPTS;
  const int cen = cidx[b * NCTR + m];
  const float cx = cb[cen], cy = cb[NPTS + cen], cz = cb[2 * NPTS + cen];
  int* outp = nidx + ((size_t)b * NCTR + m) * KNN;
  const float RR = (float)(0.2 * 0.2);   // exact f64->f32 like numpy
  int found = 0, first = -1;
  for (int chunk = 0; chunk < NPTS / 64 && found < KNN; ++chunk) {
    int p = chunk * 64 + lane;
    float dx = __fsub_rn(cx, cb[p]);
    float dy = __fsub_rn(cy, cb[NPTS + p]);
    float dz = __fsub_rn(cz, cb[2 * NPTS + p]);
    float d2 = __fadd_rn(__fadd_rn(__fmul_rn(dx, dx), __fmul_rn(dy, dy)), __fmul_rn(dz, dz));
    bool pred = d2 < RR;
    unsigned long long mask = __ballot(pred);
    if (pred) {
      int rank = __popcll(mask & ((1ull << lane) - 1ull));
      int slot = found + rank;
      if (slot < KNN) outp[slot] = p;
    }
    if (first < 0 && mask != 0ull) first = chunk * 64 + __builtin_ctzll(mask);
    found += __popcll(mask);
  }
  if (found < KNN) {
    int f = (first < 0) ? 0 : first;
    if (lane >= found) outp[lane] = f;
  }
}

// ---------------- fused conv chain: 512 thr, 8 waves, 2 waves per group (race-fixed) ----------------
// Wave wv = group*2 + hp; the pair shares one group's X tile; each wave computes
// output channels o in [hp*64, hp*64+64). 2 waves/SIMD hide staging latency.
// NL=1: conv0 -> stats0.  NL=2: conv0->bn0->conv1 -> stats1 (+y1 if WRITEY1).
// NL=3: (READY1 ? y1 : conv0->bn0->conv1) -> bn1 -> conv2 -> per-group max/min + stats2.
template <int NL, bool READY1, bool WRITEY1>
__global__ __launch_bounds__(512) void fused_kernel(
    const unsigned short* __restrict__ fT, const float* __restrict__ coords,
    const int* __restrict__ cidx, const int* __restrict__ nidx,
    unsigned short* __restrict__ y1, const float* __restrict__ ss,
    const float* __restrict__ w0, const float* __restrict__ b0,
    const float* __restrict__ w1, const float* __restrict__ b1,
    const float* __restrict__ w2, const float* __restrict__ b2,
    float* __restrict__ psum, float* __restrict__ psqr,
    float* __restrict__ gmax, float* __restrict__ gmin) {
  __shared__ __align__(16) unsigned short Xs[4 * 64 * 128];   // 64 KB
  __shared__ __align__(16) unsigned short Wbuf[128 * 128];    // 32 KB
  __shared__ float s_bias[128];
  __shared__ float s_sc0[128], s_sh0[128], s_sc1[128], s_sh1[128];
  __shared__ float s_rs[8][64], s_rq[8][64];

  const int t = threadIdx.x;
  const int wv = t >> 6, lane = t & 63;
  const int wg = wv >> 1;          // group 0..3
  const int hp = wv & 1;           // output-half parity
  const int r16 = lane & 15, kg = lane >> 4;
  const int g = blockIdx.x * 4 + wg;
  const int bb_ = g >> 10;
  const int rsw = lane & 7;
  unsigned short* xrow = &Xs[(wg * 64 + lane) * 128];

  if constexpr (NL >= 2 && !READY1) {
    if (t < 128) { s_sc0[t] = ss[t]; s_sh0[t] = ss[128 + t]; }
  }
  if constexpr (NL >= 3) {
    if (t < 128) { s_sc1[t] = ss[256 + t]; s_sh1[t] = ss[384 + t]; }
  }

  auto stageW = [&](const float* w, const float* bia, bool remap0, int oh) {
    for (int e = t; e < 128 * 128; e += 512) {
      int o = e >> 7, c = e & 127;
      float v;
      if (remap0) {
        int lc = (c < 64) ? (c + 3) : ((c < 67) ? (c - 64) : -1);
        v = (lc >= 0) ? w[o * 67 + lc] : 0.f;
      } else {
        v = w[((size_t)(oh * 128 + o)) * 128 + c];
      }
      Wbuf[(o << 7) + ((((c >> 3) ^ (o & 7)) << 3) | (c & 7))] = f2b(v);
    }
    if (t < 128) s_bias[t] = bia[oh * 128 + t];
  };

  // per-wave partials over its 4 nt tiles (channels hp*64 + k*16 + r16)
  auto statsOut = [&](float (&sv4)[4], float (&sq4)[4], int coff) {
#pragma unroll
    for (int k = 0; k < 4; ++k) {
      sv4[k] += __shfl_xor(sv4[k], 16); sv4[k] += __shfl_xor(sv4[k], 32);
      sq4[k] += __shfl_xor(sq4[k], 16); sq4[k] += __shfl_xor(sq4[k], 32);
    }
    if (lane < 16) {
#pragma unroll
      for (int k = 0; k < 4; ++k) {
        s_rs[wv][k * 16 + lane] = sv4[k];
        s_rq[wv][k * 16 + lane] = sq4[k];
      }
    }
    __syncthreads();
    if (t < 128) {
      int hp2 = t >> 6, cl = t & 63;
      float sB = s_rs[0 + hp2][cl] + s_rs[2 + hp2][cl] + s_rs[4 + hp2][cl] + s_rs[6 + hp2][cl];
      float qB = s_rq[0 + hp2][cl] + s_rq[2 + hp2][cl] + s_rq[4 + hp2][cl] + s_rq[6 + hp2][cl];
      psum[(size_t)blockIdx.x * 256 + coff + t] = sB;
      psqr[(size_t)blockIdx.x * 256 + coff + t] = qB;
    }
  };

  short8v a[4][4];

  if constexpr (!READY1) {
    if (hp == 0) {  // even wave stages its group's X0 (lane = row)
      int j = nidx[(size_t)g * KNN + lane];
      int cen = cidx[g];
      const unsigned short* fr = fT + ((size_t)bb_ * NPTS + j) * 64;
#pragma unroll
      for (int ch = 0; ch < 8; ++ch)
        *(ushort8*)(xrow + ((ch ^ rsw) << 3)) = *(const ushort8*)(fr + ch * 8);
      const float* cb = coords + (size_t)bb_ * 3 * NPTS;
      float rx = __fsub_rn(cb[j], cb[cen]);
      float ry = __fsub_rn(cb[NPTS + j], cb[NPTS + cen]);
      float rz = __fsub_rn(cb[2 * NPTS + j], cb[2 * NPTS + cen]);
      ushort8 rv = {f2b(rx), f2b(ry), f2b(rz), 0, 0, 0, 0, 0};
      *(ushort8*)(xrow + ((8 ^ rsw) << 3)) = rv;
      ushort8 zz = {0, 0, 0, 0, 0, 0, 0, 0};
#pragma unroll
      for (int ch = 9; ch < 16; ++ch)
        *(ushort8*)(xrow + ((ch ^ rsw) << 3)) = zz;
    }
    stageW(w0, b0, true, 0);
    __syncthreads();

    // ---- layer 0 ----
#pragma unroll
    for (int st = 0; st < 4; ++st) {
      int row = st * 16 + r16;
#pragma unroll
      for (int ks = 0; ks < 3; ++ks)
        a[st][ks] = __builtin_bit_cast(short8v,
            *(const ushort8*)&Xs[(wg * 64 + row) * 128 + (((ks * 4 + kg) ^ (row & 7)) << 3)]);
    }
    if constexpr (NL >= 2) __syncthreads();   // race fix: all a-loads before epilogue Xs writes
    {
      float sv4[4], sq4[4];
#pragma unroll
      for (int k = 0; k < 4; ++k) { sv4[k] = 0.f; sq4[k] = 0.f; }
#pragma unroll
      for (int k = 0; k < 4; ++k) {
        int o = hp * 64 + k * 16 + r16;
        short8v wb[3];
#pragma unroll
        for (int ks = 0; ks < 3; ++ks)
          wb[ks] = __builtin_bit_cast(short8v,
              *(const ushort8*)&Wbuf[(o << 7) + (((ks * 4 + kg) ^ (o & 7)) << 3)]);
        float bia = s_bias[o];
        float sc = 0.f, sh = 0.f;
        if constexpr (NL >= 2) { sc = s_sc0[o]; sh = s_sh0[o]; }
#pragma unroll
        for (int st = 0; st < 4; ++st) {
          f32x4 acc = {0.f, 0.f, 0.f, 0.f};
#pragma unroll
          for (int ks = 0; ks < 3; ++ks)
            acc = __builtin_amdgcn_mfma_f32_16x16x32_bf16(a[st][ks], wb[ks], acc, 0, 0, 0);
#pragma unroll
          for (int r = 0; r < 4; ++r) {
            float v = acc[r] + bia;
            if constexpr (NL == 1) {
              sv4[k] += v; sq4[k] = fmaf(v, v, sq4[k]);
            } else {
              float x = fmaxf(fmaf(v, sc, sh), 0.f);
              int row = st * 16 + kg * 4 + r;
              Xs[(wg * 64 + row) * 128 + ((((o >> 3) ^ (row & 7)) << 3) | (o & 7))] = f2b(x);
            }
          }
        }
      }
      if constexpr (NL == 1) { statsOut(sv4, sq4, 0); return; }
    }

    // ---- layer 1 ----
    if constexpr (NL >= 2) {
      __syncthreads();
      stageW(w1, b1, false, 0);
      __syncthreads();
#pragma unroll
      for (int st = 0; st < 4; ++st) {
        int row = st * 16 + r16;
#pragma unroll
        for (int ks = 0; ks < 4; ++ks)
          a[st][ks] = __builtin_bit_cast(short8v,
              *(const ushort8*)&Xs[(wg * 64 + row) * 128 + (((ks * 4 + kg) ^ (row & 7)) << 3)]);
      }
      if constexpr (NL >= 3) __syncthreads();   // race fix: a-loads before bn1 Xs writes
      float sv4[4], sq4[4];
#pragma unroll
      for (int k = 0; k < 4; ++k) { sv4[k] = 0.f; sq4[k] = 0.f; }
#pragma unroll
      for (int k = 0; k < 4; ++k) {
        int o = hp * 64 + k * 16 + r16;
        short8v wb[4];
#pragma unroll
        for (int ks = 0; ks < 4; ++ks)
          wb[ks] = __builtin_bit_cast(short8v,
              *(const ushort8*)&Wbuf[(o << 7) + (((ks * 4 + kg) ^ (o & 7)) << 3)]);
        float bia = s_bias[o];
        float sc = 0.f, sh = 0.f;
        if constexpr (NL >= 3) { sc = s_sc1[o]; sh = s_sh1[o]; }
#pragma unroll
        for (int st = 0; st < 4; ++st) {
          f32x4 acc = {0.f, 0.f, 0.f, 0.f};
#pragma unroll
          for (int ks = 0; ks < 4; ++ks)
            acc = __builtin_amdgcn_mfma_f32_16x16x32_bf16(a[st][ks], wb[ks], acc, 0, 0, 0);
#pragma unroll
          for (int r = 0; r < 4; ++r) {
            float v = acc[r] + bia;
            int row = st * 16 + kg * 4 + r;
            if constexpr (NL == 2) {
              sv4[k] += v; sq4[k] = fmaf(v, v, sq4[k]);
              if constexpr (WRITEY1)
                y1[((size_t)g * 64 + row) * 128 + o] = f2b(v);
            } else {
              float x = fmaxf(fmaf(v, sc, sh), 0.f);
              Xs[(wg * 64 + row) * 128 + ((((o >> 3) ^ (row & 7)) << 3) | (o & 7))] = f2b(x);
            }
          }
        }
      }
      if constexpr (NL == 2) { statsOut(sv4, sq4, 0); return; }
    }
  } else {
    // READY1 (NL==3): even wave stages X2 = relu(bn1(y1)) for its group
    __syncthreads();   // s_sc1/s_sh1 ready
    if (hp == 0) {
      const unsigned short* yr = y1 + ((size_t)g * 64 + lane) * 128;
#pragma unroll
      for (int ch = 0; ch < 16; ++ch) {
        ushort8 vv = *(const ushort8*)(yr + ch * 8);
        ushort8 ov;
#pragma unroll
        for (int jj = 0; jj < 8; ++jj) {
          int c = ch * 8 + jj;
          ov[jj] = f2b(fmaxf(fmaf(b2f(vv[jj]), s_sc1[c], s_sh1[c]), 0.f));
        }
        *(ushort8*)(xrow + ((ch ^ rsw) << 3)) = ov;
      }
    }
  }

  // ---- layer 2 (NL==3): two output halves, max/min + stats ----
  if constexpr (NL == 3) {
    __syncthreads();   // X2 tile complete (staged/written by partner waves)
#pragma unroll
    for (int st = 0; st < 4; ++st) {
      int row = st * 16 + r16;
#pragma unroll
      for (int ks = 0; ks < 4; ++ks)
        a[st][ks] = __builtin_bit_cast(short8v,
            *(const ushort8*)&Xs[(wg * 64 + row) * 128 + (((ks * 4 + kg) ^ (row & 7)) << 3)]);
    }
    for (int h = 0; h < 2; ++h) {
      __syncthreads();
      stageW(w2, b2, false, h);
      __syncthreads();
      float mx4[4], mn4[4], sv4[4], sq4[4];
#pragma unroll
      for (int k = 0; k < 4; ++k) { mx4[k] = -1e30f; mn4[k] = 1e30f; sv4[k] = 0.f; sq4[k] = 0.f; }
#pragma unroll
      for (int k = 0; k < 4; ++k) {
        int o = hp * 64 + k * 16 + r16;
        short8v wb[4];
#pragma unroll
        for (int ks = 0; ks < 4; ++ks)
          wb[ks] = __builtin_bit_cast(short8v,
              *(const ushort8*)&Wbuf[(o << 7) + (((ks * 4 + kg) ^ (o & 7)) << 3)]);
        float bia = s_bias[o];
#pragma unroll
        for (int st = 0; st < 4; ++st) {
          f32x4 acc = {0.f, 0.f, 0.f, 0.f};
#pragma unroll
          for (int ks = 0; ks < 4; ++ks)
            acc = __builtin_amdgcn_mfma_f32_16x16x32_bf16(a[st][ks], wb[ks], acc, 0, 0, 0);
#pragma unroll
          for (int r = 0; r < 4; ++r) {
            float v = acc[r] + bia;
            mx4[k] = fmaxf(mx4[k], v); mn4[k] = fminf(mn4[k], v);
            sv4[k] += v; sq4[k] = fmaf(v, v, sq4[k]);
          }
        }
      }
#pragma unroll
      for (int k = 0; k < 4; ++k) {
        mx4[k] = fmaxf(mx4[k], __shfl_xor(mx4[k], 16));
        mx4[k] = fmaxf(mx4[k], __shfl_xor(mx4[k], 32));
        mn4[k] = fminf(mn4[k], __shfl_xor(mn4[k], 16));
        mn4[k] = fminf(mn4[k], __shfl_xor(mn4[k], 32));
      }
      if (lane < 16) {
#pragma unroll
        for (int k = 0; k < 4; ++k) {
          gmax[(size_t)g * 256 + h * 128 + hp * 64 + k * 16 + lane] = mx4[k];
          gmin[(size_t)g * 256 + h * 128 + hp * 64 + k * 16 + lane] = mn4[k];
        }
      }
      statsOut(sv4, sq4, h * 128);
    }
  }
}

// ---------------- stats finalize (2048 partial rows) ----------------
template <int O>
__global__ __launch_bounds__(256) void ss_kernel(const float* __restrict__ psum,
                                                 const float* __restrict__ psqr,
                                                 const float* __restrict__ gamma,
                                                 const float* __restrict__ beta,
                                                 float* __restrict__ ss_out) {
  int c = blockIdx.x;
  int t = threadIdx.x;
  float s = 0.f, q = 0.f;
  for (int i = t; i < 2048; i += 256) {
    s += psum[(size_t)i * 256 + c];
    q += psqr[(size_t)i * 256 + c];
  }
  int lane = t & 63, wid = t >> 6;
#pragma unroll
  for (int off = 32; off > 0; off >>= 1) { s += __shfl_down(s, off); q += __shfl_down(q, off); }
  __shared__ float rv[4], rqv[4];
  if (lane == 0) { rv[wid] = s; rqv[wid] = q; }
  __syncthreads();
  if (t == 0) {
    s = rv[0] + rv[1] + rv[2] + rv[3];
    q = rqv[0] + rqv[1] + rqv[2] + rqv[3];
    const float inv = 1.0f / (float)SAMP;
    float mu = s * inv;
    float var = fmaxf(q * inv - mu * mu, 0.f);
    float rs = 1.0f / sqrtf(var + EPSB);
    float sc = gamma[c] * rs;
    ss_out[c] = sc;
    ss_out[O + c] = beta[c] - mu * sc;
  }
}

// ---------------- final: out = relu(max(sc*mx+sh, sc*mn+sh)), LDS transpose ----------------
__global__ __launch_bounds__(256) void final_kernel(const float* __restrict__ gmax,
                                                    const float* __restrict__ gmin,
                                                    const float* __restrict__ ss2,
                                                    float* __restrict__ out) {
  int b = blockIdx.x >> 5, mt = blockIdx.x & 31;
  int t = threadIdx.x;
  __shared__ float tile[32][257];
  float sc = ss2[t], sh = ss2[256 + t];
  size_t base = ((size_t)b * 1024 + mt * 32) * 256;
#pragma unroll
  for (int r = 0; r < 32; ++r) {
    float A = fmaf(gmax[base + r * 256 + t], sc, sh);
    float C = fmaf(gmin[base + r * 256 + t], sc, sh);
    tile[r][t] = fmaxf(fmaxf(A, C), 0.f);
  }
  __syncthreads();
  for (int i = t; i < 8192; i += 256) {
    int o = i >> 5, ml = i & 31;
    out[((size_t)b * 256 + o) * 1024 + mt * 32 + ml] = tile[ml][o];
  }
}

__global__ void cond_kernel(const float* __restrict__ cond, float* __restrict__ dst) {
  dst[threadIdx.x] = cond[threadIdx.x];
}

extern "C" void kernel_launch(void* const* d_in, const int* in_sizes, int n_in,
                              void* d_out, int out_size, void* d_ws, size_t ws_size,
                              hipStream_t stream) {
  const float* feat   = (const float*)d_in[0];
  const float* coords = (const float*)d_in[1];
  const float* cond   = (const float*)d_in[2];
  const float* w0  = (const float*)d_in[3];
  const float* b0  = (const float*)d_in[4];
  const float* ga0 = (const float*)d_in[5];
  const float* be0 = (const float*)d_in[6];
  const float* w1  = (const float*)d_in[7];
  const float* b1  = (const float*)d_in[8];
  const float* ga1 = (const float*)d_in[9];
  const float* be1 = (const float*)d_in[10];
  const float* w2  = (const float*)d_in[11];
  const float* b2  = (const float*)d_in[12];
  const float* ga2 = (const float*)d_in[13];
  const float* be2 = (const float*)d_in[14];

  char* ws = (char*)d_ws;
  int* cidxp = (int*)(ws + OFF_CIDX);
  int* nidxp = (int*)(ws + OFF_NIDX);
  float* ss   = (float*)(ws + OFF_SS);
  float* psum = (float*)(ws + OFF_PSUM);
  float* psqr = (float*)(ws + OFF_PSQR);
  float* gmax = (float*)(ws + OFF_GMAX);
  float* gmin = (float*)(ws + OFF_GMIN);
  unsigned short* fT = (unsigned short*)(ws + OFF_FT);
  unsigned short* y1 = (unsigned short*)(ws + OFF_Y1);

  float* out         = (float*)d_out;
  float* centers_out = out + (size_t)8 * 256 * 1024;
  float* cond_out    = centers_out + (size_t)8 * 3 * 1024;

  const bool big = (ws_size >= NEED_BIG);

  fps_kernel<<<8, 256, 0, stream>>>(coords, cidxp, centers_out);
  featT_kernel<<<dim3(128, 8), 256, 0, stream>>>(feat, fT);
  bq_kernel<<<dim3(256, 8), 256, 0, stream>>>(coords, cidxp, nidxp);

  fused_kernel<1, false, false><<<2048, 512, 0, stream>>>(
      fT, coords, cidxp, nidxp, y1, ss, w0, b0, w1, b1, w2, b2, psum, psqr, gmax, gmin);
  ss_kernel<128><<<128, 256, 0, stream>>>(psum, psqr, ga0, be0, ss);

  if (big) {
    fused_kernel<2, false, true><<<2048, 512, 0, stream>>>(
        fT, coords, cidxp, nidxp, y1, ss, w0, b0, w1, b1, w2, b2, psum, psqr, gmax, gmin);
  } else {
    fused_kernel<2, false, false><<<2048, 512, 0, stream>>>(
        fT, coords, cidxp, nidxp, y1, ss, w0, b0, w1, b1, w2, b2, psum, psqr, gmax, gmin);
  }
  ss_kernel<128><<<128, 256, 0, stream>>>(psum, psqr, ga1, be1, ss + 256);

  if (big) {
    fused_kernel<3, true, false><<<2048, 512, 0, stream>>>(
        fT, coords, cidxp, nidxp, y1, ss, w0, b0, w1, b1, w2, b2, psum, psqr, gmax, gmin);
  } else {
    fused_kernel<3, false, false><<<2048, 512, 0, stream>>>(
        fT, coords, cidxp, nidxp, y1, ss, w0, b0, w1, b1, w2, b2, psum, psqr, gmax, gmin);
  }
  ss_kernel<256><<<256, 256, 0, stream>>>(psum, psqr, ga2, be2, ss + 512);

  final_kernel<<<256, 256, 0, stream>>>(gmax, gmin, ss + 512, out);
  cond_kernel<<<1, 512, 0, stream>>>(cond, cond_out);
}

// Round 12
// 1315.819 us; speedup vs baseline: 1.0867x; 1.0269x over previous
//
#include <hip/hip_runtime.h>

#define NB    8
#define NPTS  8192
#define NCTR  1024
#define KNN   64
#define NGRP  8192
#define SAMP  524288
#define EPSB  1e-5f

// ---- ws layout (bytes), total SMALL = ~31.5 MB, BIG = ~166 MB ----
#define OFF_CIDX 0ull
#define OFF_NIDX 32768ull
#define OFF_SS   2129920ull
#define OFF_PSUM 2134016ull
#define OFF_PSQR 4231168ull
#define OFF_GMAX 6328320ull
#define OFF_GMIN 14716928ull
#define OFF_FT   23105536ull
#define OFF_Y1   31494144ull
#define NEED_BIG 165711872ull

typedef unsigned short ushort8 __attribute__((ext_vector_type(8)));
typedef short short8v __attribute__((ext_vector_type(8)));
typedef float f32x4 __attribute__((ext_vector_type(4)));

__device__ __forceinline__ unsigned short f2b(float f) {
  unsigned int u = __builtin_bit_cast(unsigned int, f);
  u += 0x7fffu + ((u >> 16) & 1u);
  return (unsigned short)(u >> 16);
}
__device__ __forceinline__ float b2f(unsigned short s) {
  unsigned int u = ((unsigned int)s) << 16;
  return __builtin_bit_cast(float, u);
}

// DPP-assisted max step: r = max(r, dpp_move(r)) ; bound_ctrl=1 -> invalid src reads 0.0
// (identity for non-negative distances).
template <int CTRL>
__device__ __forceinline__ float dppmax(float x) {
  int m = __builtin_amdgcn_update_dpp(0, __builtin_bit_cast(int, x), CTRL, 0xf, 0xf, true);
  return fmaxf(x, __builtin_bit_cast(float, m));
}

// ---------------- FPS (R5 exact, best measured): 4 waves, DPP wave-max + ballot ----------------
// Thread t owns contiguous points [t*32, t*32+32) -> lane order == index order, so
// ballot+ctz after the max reduce picks the smallest index (numpy first-occurrence).
// Inter-wave: u64 pack (bits(dist)<<32)|~idx; max == (max dist, then min idx).
__global__ __launch_bounds__(256) void fps_kernel(const float* __restrict__ coords,
                                                  int* __restrict__ cidx,
                                                  float* __restrict__ centers_out) {
  const int b = blockIdx.x;
  const int t = threadIdx.x;
  const int wid = t >> 6, lane = t & 63;
  __shared__ float4 sc4[NPTS];                 // 128 KB packed coords
  __shared__ unsigned long long red[2][4];
  const float* cb = coords + (size_t)b * 3 * NPTS;
  for (int i = t; i < NPTS; i += 256)
    sc4[i] = make_float4(cb[i], cb[NPTS + i], cb[2 * NPTS + i], 0.f);
  __syncthreads();
  constexpr int PT = NPTS / 256;  // 32, contiguous per thread
  float px[PT], py[PT], pz[PT], dst[PT];
#pragma unroll
  for (int i = 0; i < PT; ++i) {
    int p = t * PT + i;
    px[i] = cb[p]; py[i] = cb[NPTS + p]; pz[i] = cb[2 * NPTS + p];
    dst[i] = 1e10f;
  }
  int cur = 0;
  float4 c0 = sc4[0];
  float cx = c0.x, cy = c0.y, cz = c0.z;
  int parity = 0;
  for (int s = 0; s < NCTR; ++s) {
    if (t == 0) {
      cidx[b * NCTR + s] = cur;
      centers_out[(b * 3 + 0) * NCTR + s] = cx;
      centers_out[(b * 3 + 1) * NCTR + s] = cy;
      centers_out[(b * 3 + 2) * NCTR + s] = cz;
    }
    float bv = -1.0f; int bi = 0;
#pragma unroll
    for (int i = 0; i < PT; ++i) {
      // exact numpy f32 order: ((dx*dx + dy*dy) + dz*dz), no fma contraction
      float dx = __fsub_rn(px[i], cx);
      float dy = __fsub_rn(py[i], cy);
      float dz = __fsub_rn(pz[i], cz);
      float d2 = __fadd_rn(__fadd_rn(__fmul_rn(dx, dx), __fmul_rn(dy, dy)), __fmul_rn(dz, dz));
      float nd = fminf(dst[i], d2);
      dst[i] = nd;
      if (nd > bv) { bv = nd; bi = t * PT + i; }   // ascending i -> first occurrence
    }
    // in-wave max via DPP: row_shr 1/2/4/8 then row_bcast15/31; lane 63 holds wave max
    float r = bv;
    r = dppmax<0x111>(r);
    r = dppmax<0x112>(r);
    r = dppmax<0x114>(r);
    r = dppmax<0x118>(r);
    r = dppmax<0x142>(r);
    r = dppmax<0x143>(r);
    float wm = __builtin_bit_cast(float,
        __builtin_amdgcn_readlane(__builtin_bit_cast(int, r), 63));
    unsigned long long mask = __ballot(bv == wm);
    int widx = __shfl(bi, (int)__builtin_ctzll(mask));  // lowest lane == smallest index
    if (lane == 0)
      red[parity][wid] =
          ((unsigned long long)__builtin_bit_cast(unsigned int, wm) << 32) |
          (unsigned long long)(~(unsigned int)widx);
    __syncthreads();
    unsigned long long best = red[parity][0];
#pragma unroll
    for (int k = 1; k < 4; ++k) {
      unsigned long long o = red[parity][k];
      best = (o > best) ? o : best;
    }
    cur = (int)(~(unsigned int)best);
    float4 cc = sc4[cur];                       // single b128 LDS broadcast
    cx = cc.x; cy = cc.y; cz = cc.z;
    parity ^= 1;
  }
}

// ---------------- feat transpose to [B][N][64] bf16 ----------------
__global__ __launch_bounds__(256) void featT_kernel(const float* __restrict__ feat,
                                                    unsigned short* __restrict__ fT) {
  int b  = blockIdx.y;
  int j  = blockIdx.x * 64 + (threadIdx.x & 63);
  int cg = threadIdx.x >> 6;
  ushort8 v0, v1;
#pragma unroll
  for (int cc = 0; cc < 8; ++cc)
    v0[cc] = f2b(feat[((size_t)b * 64 + cg * 16 + cc) * NPTS + j]);
#pragma unroll
  for (int cc = 0; cc < 8; ++cc)
    v1[cc] = f2b(feat[((size_t)b * 64 + cg * 16 + 8 + cc) * NPTS + j]);
  unsigned short* dst = fT + ((size_t)b * NPTS + j) * 64 + cg * 16;
  *(ushort8*)dst = v0;
  *(ushort8*)(dst + 8) = v1;
}

// ---------------- ball query: wave per center, stream coords from L2 ----------------
__global__ __launch_bounds__(256) void bq_kernel(const float* __restrict__ coords,
                                                 const int* __restrict__ cidx,
                                                 int* __restrict__ nidx) {
  const int b = blockIdx.y;
  const int w = threadIdx.x >> 6, lane = threadIdx.x & 63;
  const int m = blockIdx.x * 4 + w;
  const float* cb = coords + (size_t)b * 3 * NPTS;
  const int cen = cidx[b * NCTR + m];
  const float cx = cb[cen], cy = cb[NPTS + cen], cz = cb[2 * NPTS + cen];
  int* outp = nidx + ((size_t)b * NCTR + m) * KNN;
  const float RR = (float)(0.2 * 0.2);   // exact f64->f32 like numpy
  int found = 0, first = -1;
  for (int chunk = 0; chunk < NPTS / 64 && found < KNN; ++chunk) {
    int p = chunk * 64 + lane;
    float dx = __fsub_rn(cx, cb[p]);
    float dy = __fsub_rn(cy, cb[NPTS + p]);
    float dz = __fsub_rn(cz, cb[2 * NPTS + p]);
    float d2 = __fadd_rn(__fadd_rn(__fmul_rn(dx, dx), __fmul_rn(dy, dy)), __fmul_rn(dz, dz));
    bool pred = d2 < RR;
    unsigned long long mask = __ballot(pred);
    if (pred) {
      int rank = __popcll(mask & ((1ull << lane) - 1ull));
      int slot = found + rank;
      if (slot < KNN) outp[slot] = p;
    }
    if (first < 0 && mask != 0ull) first = chunk * 64 + __builtin_ctzll(mask);
    found += __popcll(mask);
  }
  if (found < KNN) {
    int f = (first < 0) ? 0 : first;
    if (lane >= found) outp[lane] = f;
  }
}

// ---------------- fused conv chain: 512 thr, 8 waves, 2 waves per group (race-fixed) ----------------
// Wave wv = group*2 + hp; the pair shares one group's X tile; each wave computes
// output channels o in [hp*64, hp*64+64). 2 waves/SIMD hide staging latency.
// NL=1: conv0 -> stats0.  NL=2: conv0->bn0->conv1 -> stats1 (+y1 if WRITEY1).
// NL=3: (READY1 ? y1 : conv0->bn0->conv1) -> bn1 -> conv2 -> per-group max/min + stats2.
template <int NL, bool READY1, bool WRITEY1>
__global__ __launch_bounds__(512) void fused_kernel(
    const unsigned short* __restrict__ fT, const float* __restrict__ coords,
    const int* __restrict__ cidx, const int* __restrict__ nidx,
    unsigned short* __restrict__ y1, const float* __restrict__ ss,
    const float* __restrict__ w0, const float* __restrict__ b0,
    const float* __restrict__ w1, const float* __restrict__ b1,
    const float* __restrict__ w2, const float* __restrict__ b2,
    float* __restrict__ psum, float* __restrict__ psqr,
    float* __restrict__ gmax, float* __restrict__ gmin) {
  __shared__ __align__(16) unsigned short Xs[4 * 64 * 128];   // 64 KB
  __shared__ __align__(16) unsigned short Wbuf[128 * 128];    // 32 KB
  __shared__ float s_bias[128];
  __shared__ float s_sc0[128], s_sh0[128], s_sc1[128], s_sh1[128];
  __shared__ float s_rs[8][64], s_rq[8][64];

  const int t = threadIdx.x;
  const int wv = t >> 6, lane = t & 63;
  const int wg = wv >> 1;          // group 0..3
  const int hp = wv & 1;           // output-half parity
  const int r16 = lane & 15, kg = lane >> 4;
  const int g = blockIdx.x * 4 + wg;
  const int bb_ = g >> 10;
  const int rsw = lane & 7;
  unsigned short* xrow = &Xs[(wg * 64 + lane) * 128];

  if constexpr (NL >= 2 && !READY1) {
    if (t < 128) { s_sc0[t] = ss[t]; s_sh0[t] = ss[128 + t]; }
  }
  if constexpr (NL >= 3) {
    if (t < 128) { s_sc1[t] = ss[256 + t]; s_sh1[t] = ss[384 + t]; }
  }

  auto stageW = [&](const float* w, const float* bia, bool remap0, int oh) {
    for (int e = t; e < 128 * 128; e += 512) {
      int o = e >> 7, c = e & 127;
      float v;
      if (remap0) {
        int lc = (c < 64) ? (c + 3) : ((c < 67) ? (c - 64) : -1);
        v = (lc >= 0) ? w[o * 67 + lc] : 0.f;
      } else {
        v = w[((size_t)(oh * 128 + o)) * 128 + c];
      }
      Wbuf[(o << 7) + ((((c >> 3) ^ (o & 7)) << 3) | (c & 7))] = f2b(v);
    }
    if (t < 128) s_bias[t] = bia[oh * 128 + t];
  };

  // per-wave partials over its 4 nt tiles (channels hp*64 + k*16 + r16)
  auto statsOut = [&](float (&sv4)[4], float (&sq4)[4], int coff) {
#pragma unroll
    for (int k = 0; k < 4; ++k) {
      sv4[k] += __shfl_xor(sv4[k], 16); sv4[k] += __shfl_xor(sv4[k], 32);
      sq4[k] += __shfl_xor(sq4[k], 16); sq4[k] += __shfl_xor(sq4[k], 32);
    }
    if (lane < 16) {
#pragma unroll
      for (int k = 0; k < 4; ++k) {
        s_rs[wv][k * 16 + lane] = sv4[k];
        s_rq[wv][k * 16 + lane] = sq4[k];
      }
    }
    __syncthreads();
    if (t < 128) {
      int hp2 = t >> 6, cl = t & 63;
      float sB = s_rs[0 + hp2][cl] + s_rs[2 + hp2][cl] + s_rs[4 + hp2][cl] + s_rs[6 + hp2][cl];
      float qB = s_rq[0 + hp2][cl] + s_rq[2 + hp2][cl] + s_rq[4 + hp2][cl] + s_rq[6 + hp2][cl];
      psum[(size_t)blockIdx.x * 256 + coff + t] = sB;
      psqr[(size_t)blockIdx.x * 256 + coff + t] = qB;
    }
  };

  short8v a[4][4];

  if constexpr (!READY1) {
    if (hp == 0) {  // even wave stages its group's X0 (lane = row)
      int j = nidx[(size_t)g * KNN + lane];
      int cen = cidx[g];
      const unsigned short* fr = fT + ((size_t)bb_ * NPTS + j) * 64;
#pragma unroll
      for (int ch = 0; ch < 8; ++ch)
        *(ushort8*)(xrow + ((ch ^ rsw) << 3)) = *(const ushort8*)(fr + ch * 8);
      const float* cb = coords + (size_t)bb_ * 3 * NPTS;
      float rx = __fsub_rn(cb[j], cb[cen]);
      float ry = __fsub_rn(cb[NPTS + j], cb[NPTS + cen]);
      float rz = __fsub_rn(cb[2 * NPTS + j], cb[2 * NPTS + cen]);
      ushort8 rv = {f2b(rx), f2b(ry), f2b(rz), 0, 0, 0, 0, 0};
      *(ushort8*)(xrow + ((8 ^ rsw) << 3)) = rv;
      ushort8 zz = {0, 0, 0, 0, 0, 0, 0, 0};
#pragma unroll
      for (int ch = 9; ch < 16; ++ch)
        *(ushort8*)(xrow + ((ch ^ rsw) << 3)) = zz;
    }
    stageW(w0, b0, true, 0);
    __syncthreads();

    // ---- layer 0 ----
#pragma unroll
    for (int st = 0; st < 4; ++st) {
      int row = st * 16 + r16;
#pragma unroll
      for (int ks = 0; ks < 3; ++ks)
        a[st][ks] = __builtin_bit_cast(short8v,
            *(const ushort8*)&Xs[(wg * 64 + row) * 128 + (((ks * 4 + kg) ^ (row & 7)) << 3)]);
    }
    if constexpr (NL >= 2) __syncthreads();   // race fix: all a-loads before epilogue Xs writes
    {
      float sv4[4], sq4[4];
#pragma unroll
      for (int k = 0; k < 4; ++k) { sv4[k] = 0.f; sq4[k] = 0.f; }
#pragma unroll
      for (int k = 0; k < 4; ++k) {
        int o = hp * 64 + k * 16 + r16;
        short8v wb[3];
#pragma unroll
        for (int ks = 0; ks < 3; ++ks)
          wb[ks] = __builtin_bit_cast(short8v,
              *(const ushort8*)&Wbuf[(o << 7) + (((ks * 4 + kg) ^ (o & 7)) << 3)]);
        float bia = s_bias[o];
        float sc = 0.f, sh = 0.f;
        if constexpr (NL >= 2) { sc = s_sc0[o]; sh = s_sh0[o]; }
#pragma unroll
        for (int st = 0; st < 4; ++st) {
          f32x4 acc = {0.f, 0.f, 0.f, 0.f};
#pragma unroll
          for (int ks = 0; ks < 3; ++ks)
            acc = __builtin_amdgcn_mfma_f32_16x16x32_bf16(a[st][ks], wb[ks], acc, 0, 0, 0);
#pragma unroll
          for (int r = 0; r < 4; ++r) {
            float v = acc[r] + bia;
            if constexpr (NL == 1) {
              sv4[k] += v; sq4[k] = fmaf(v, v, sq4[k]);
            } else {
              float x = fmaxf(fmaf(v, sc, sh), 0.f);
              int row = st * 16 + kg * 4 + r;
              Xs[(wg * 64 + row) * 128 + ((((o >> 3) ^ (row & 7)) << 3) | (o & 7))] = f2b(x);
            }
          }
        }
      }
      if constexpr (NL == 1) { statsOut(sv4, sq4, 0); return; }
    }

    // ---- layer 1 ----
    if constexpr (NL >= 2) {
      __syncthreads();
      stageW(w1, b1, false, 0);
      __syncthreads();
#pragma unroll
      for (int st = 0; st < 4; ++st) {
        int row = st * 16 + r16;
#pragma unroll
        for (int ks = 0; ks < 4; ++ks)
          a[st][ks] = __builtin_bit_cast(short8v,
              *(const ushort8*)&Xs[(wg * 64 + row) * 128 + (((ks * 4 + kg) ^ (row & 7)) << 3)]);
      }
      if constexpr (NL >= 3) __syncthreads();   // race fix: a-loads before bn1 Xs writes
      float sv4[4], sq4[4];
#pragma unroll
      for (int k = 0; k < 4; ++k) { sv4[k] = 0.f; sq4[k] = 0.f; }
#pragma unroll
      for (int k = 0; k < 4; ++k) {
        int o = hp * 64 + k * 16 + r16;
        short8v wb[4];
#pragma unroll
        for (int ks = 0; ks < 4; ++ks)
          wb[ks] = __builtin_bit_cast(short8v,
              *(const ushort8*)&Wbuf[(o << 7) + (((ks * 4 + kg) ^ (o & 7)) << 3)]);
        float bia = s_bias[o];
        float sc = 0.f, sh = 0.f;
        if constexpr (NL >= 3) { sc = s_sc1[o]; sh = s_sh1[o]; }
#pragma unroll
        for (int st = 0; st < 4; ++st) {
          f32x4 acc = {0.f, 0.f, 0.f, 0.f};
#pragma unroll
          for (int ks = 0; ks < 4; ++ks)
            acc = __builtin_amdgcn_mfma_f32_16x16x32_bf16(a[st][ks], wb[ks], acc, 0, 0, 0);
#pragma unroll
          for (int r = 0; r < 4; ++r) {
            float v = acc[r] + bia;
            int row = st * 16 + kg * 4 + r;
            if constexpr (NL == 2) {
              sv4[k] += v; sq4[k] = fmaf(v, v, sq4[k]);
              if constexpr (WRITEY1)
                y1[((size_t)g * 64 + row) * 128 + o] = f2b(v);
            } else {
              float x = fmaxf(fmaf(v, sc, sh), 0.f);
              Xs[(wg * 64 + row) * 128 + ((((o >> 3) ^ (row & 7)) << 3) | (o & 7))] = f2b(x);
            }
          }
        }
      }
      if constexpr (NL == 2) { statsOut(sv4, sq4, 0); return; }
    }
  } else {
    // READY1 (NL==3): even wave stages X2 = relu(bn1(y1)) for its group
    __syncthreads();   // s_sc1/s_sh1 ready
    if (hp == 0) {
      const unsigned short* yr = y1 + ((size_t)g * 64 + lane) * 128;
#pragma unroll
      for (int ch = 0; ch < 16; ++ch) {
        ushort8 vv = *(const ushort8*)(yr + ch * 8);
        ushort8 ov;
#pragma unroll
        for (int jj = 0; jj < 8; ++jj) {
          int c = ch * 8 + jj;
          ov[jj] = f2b(fmaxf(fmaf(b2f(vv[jj]), s_sc1[c], s_sh1[c]), 0.f));
        }
        *(ushort8*)(xrow + ((ch ^ rsw) << 3)) = ov;
      }
    }
  }

  // ---- layer 2 (NL==3): two output halves, max/min + stats ----
  if constexpr (NL == 3) {
    __syncthreads();   // X2 tile complete (staged/written by partner waves)
#pragma unroll
    for (int st = 0; st < 4; ++st) {
      int row = st * 16 + r16;
#pragma unroll
      for (int ks = 0; ks < 4; ++ks)
        a[st][ks] = __builtin_bit_cast(short8v,
            *(const ushort8*)&Xs[(wg * 64 + row) * 128 + (((ks * 4 + kg) ^ (row & 7)) << 3)]);
    }
    for (int h = 0; h < 2; ++h) {
      __syncthreads();
      stageW(w2, b2, false, h);
      __syncthreads();
      float mx4[4], mn4[4], sv4[4], sq4[4];
#pragma unroll
      for (int k = 0; k < 4; ++k) { mx4[k] = -1e30f; mn4[k] = 1e30f; sv4[k] = 0.f; sq4[k] = 0.f; }
#pragma unroll
      for (int k = 0; k < 4; ++k) {
        int o = hp * 64 + k * 16 + r16;
        short8v wb[4];
#pragma unroll
        for (int ks = 0; ks < 4; ++ks)
          wb[ks] = __builtin_bit_cast(short8v,
              *(const ushort8*)&Wbuf[(o << 7) + (((ks * 4 + kg) ^ (o & 7)) << 3)]);
        float bia = s_bias[o];
#pragma unroll
        for (int st = 0; st < 4; ++st) {
          f32x4 acc = {0.f, 0.f, 0.f, 0.f};
#pragma unroll
          for (int ks = 0; ks < 4; ++ks)
            acc = __builtin_amdgcn_mfma_f32_16x16x32_bf16(a[st][ks], wb[ks], acc, 0, 0, 0);
#pragma unroll
          for (int r = 0; r < 4; ++r) {
            float v = acc[r] + bia;
            mx4[k] = fmaxf(mx4[k], v); mn4[k] = fminf(mn4[k], v);
            sv4[k] += v; sq4[k] = fmaf(v, v, sq4[k]);
          }
        }
      }
#pragma unroll
      for (int k = 0; k < 4; ++k) {
        mx4[k] = fmaxf(mx4[k], __shfl_xor(mx4[k], 16));
        mx4[k] = fmaxf(mx4[k], __shfl_xor(mx4[k], 32));
        mn4[k] = fminf(mn4[k], __shfl_xor(mn4[k], 16));
        mn4[k] = fminf(mn4[k], __shfl_xor(mn4[k], 32));
      }
      if (lane < 16) {
#pragma unroll
        for (int k = 0; k < 4; ++k) {
          gmax[(size_t)g * 256 + h * 128 + hp * 64 + k * 16 + lane] = mx4[k];
          gmin[(size_t)g * 256 + h * 128 + hp * 64 + k * 16 + lane] = mn4[k];
        }
      }
      statsOut(sv4, sq4, h * 128);
    }
  }
}

// ---------------- stats finalize (2048 partial rows) ----------------
template <int O>
__global__ __launch_bounds__(256) void ss_kernel(const float* __restrict__ psum,
                                                 const float* __restrict__ psqr,
                                                 const float* __restrict__ gamma,
                                                 const float* __restrict__ beta,
                                                 float* __restrict__ ss_out) {
  int c = blockIdx.x;
  int t = threadIdx.x;
  float s = 0.f, q = 0.f;
  for (int i = t; i < 2048; i += 256) {
    s += psum[(size_t)i * 256 + c];
    q += psqr[(size_t)i * 256 + c];
  }
  int lane = t & 63, wid = t >> 6;
#pragma unroll
  for (int off = 32; off > 0; off >>= 1) { s += __shfl_down(s, off); q += __shfl_down(q, off); }
  __shared__ float rv[4], rqv[4];
  if (lane == 0) { rv[wid] = s; rqv[wid] = q; }
  __syncthreads();
  if (t == 0) {
    s = rv[0] + rv[1] + rv[2] + rv[3];
    q = rqv[0] + rqv[1] + rqv[2] + rqv[3];
    const float inv = 1.0f / (float)SAMP;
    float mu = s * inv;
    float var = fmaxf(q * inv - mu * mu, 0.f);
    float rs = 1.0f / sqrtf(var + EPSB);
    float sc = gamma[c] * rs;
    ss_out[c] = sc;
    ss_out[O + c] = beta[c] - mu * sc;
  }
}

// ---------------- final: out = relu(max(sc*mx+sh, sc*mn+sh)), LDS transpose ----------------
__global__ __launch_bounds__(256) void final_kernel(const float* __restrict__ gmax,
                                                    const float* __restrict__ gmin,
                                                    const float* __restrict__ ss2,
                                                    float* __restrict__ out) {
  int b = blockIdx.x >> 5, mt = blockIdx.x & 31;
  int t = threadIdx.x;
  __shared__ float tile[32][257];
  float sc = ss2[t], sh = ss2[256 + t];
  size_t base = ((size_t)b * 1024 + mt * 32) * 256;
#pragma unroll
  for (int r = 0; r < 32; ++r) {
    float A = fmaf(gmax[base + r * 256 + t], sc, sh);
    float C = fmaf(gmin[base + r * 256 + t], sc, sh);
    tile[r][t] = fmaxf(fmaxf(A, C), 0.f);
  }
  __syncthreads();
  for (int i = t; i < 8192; i += 256) {
    int o = i >> 5, ml = i & 31;
    out[((size_t)b * 256 + o) * 1024 + mt * 32 + ml] = tile[ml][o];
  }
}

__global__ void cond_kernel(const float* __restrict__ cond, float* __restrict__ dst) {
  dst[threadIdx.x] = cond[threadIdx.x];
}

extern "C" void kernel_launch(void* const* d_in, const int* in_sizes, int n_in,
                              void* d_out, int out_size, void* d_ws, size_t ws_size,
                              hipStream_t stream) {
  const float* feat   = (const float*)d_in[0];
  const float* coords = (const float*)d_in[1];
  const float* cond   = (const float*)d_in[2];
  const float* w0  = (const float*)d_in[3];
  const float* b0  = (const float*)d_in[4];
  const float* ga0 = (const float*)d_in[5];
  const float* be0 = (const float*)d_in[6];
  const float* w1  = (const float*)d_in[7];
  const float* b1  = (const float*)d_in[8];
  const float* ga1 = (const float*)d_in[9];
  const float* be1 = (const float*)d_in[10];
  const float* w2  = (const float*)d_in[11];
  const float* b2  = (const float*)d_in[12];
  const float* ga2 = (const float*)d_in[13];
  const float* be2 = (const float*)d_in[14];

  char* ws = (char*)d_ws;
  int* cidxp = (int*)(ws + OFF_CIDX);
  int* nidxp = (int*)(ws + OFF_NIDX);
  float* ss   = (float*)(ws + OFF_SS);
  float* psum = (float*)(ws + OFF_PSUM);
  float* psqr = (float*)(ws + OFF_PSQR);
  float* gmax = (float*)(ws + OFF_GMAX);
  float* gmin = (float*)(ws + OFF_GMIN);
  unsigned short* fT = (unsigned short*)(ws + OFF_FT);
  unsigned short* y1 = (unsigned short*)(ws + OFF_Y1);

  float* out         = (float*)d_out;
  float* centers_out = out + (size_t)8 * 256 * 1024;
  float* cond_out    = centers_out + (size_t)8 * 3 * 1024;

  const bool big = (ws_size >= NEED_BIG);

  fps_kernel<<<8, 256, 0, stream>>>(coords, cidxp, centers_out);
  featT_kernel<<<dim3(128, 8), 256, 0, stream>>>(feat, fT);
  bq_kernel<<<dim3(256, 8), 256, 0, stream>>>(coords, cidxp, nidxp);

  fused_kernel<1, false, false><<<2048, 512, 0, stream>>>(
      fT, coords, cidxp, nidxp, y1, ss, w0, b0, w1, b1, w2, b2, psum, psqr, gmax, gmin);
  ss_kernel<128><<<128, 256, 0, stream>>>(psum, psqr, ga0, be0, ss);

  if (big) {
    fused_kernel<2, false, true><<<2048, 512, 0, stream>>>(
        fT, coords, cidxp, nidxp, y1, ss, w0, b0, w1, b1, w2, b2, psum, psqr, gmax, gmin);
  } else {
    fused_kernel<2, false, false><<<2048, 512, 0, stream>>>(
        fT, coords, cidxp, nidxp, y1, ss, w0, b0, w1, b1, w2, b2, psum, psqr, gmax, gmin);
  }
  ss_kernel<128><<<128, 256, 0, stream>>>(psum, psqr, ga1, be1, ss + 256);

  if (big) {
    fused_kernel<3, true, false><<<2048, 512, 0, stream>>>(
        fT, coords, cidxp, nidxp, y1, ss, w0, b0, w1, b1, w2, b2, psum, psqr, gmax, gmin);
  } else {
    fused_kernel<3, false, false><<<2048, 512, 0, stream>>>(
        fT, coords, cidxp, nidxp, y1, ss, w0, b0, w1, b1, w2, b2, psum, psqr, gmax, gmin);
  }
  ss_kernel<256><<<256, 256, 0, stream>>>(psum, psqr, ga2, be2, ss + 512);

  final_kernel<<<256, 256, 0, stream>>>(gmax, gmin, ss + 512, out);
  cond_kernel<<<1, 512, 0, stream>>>(cond, cond_out);
}